// Round 1
// baseline (1899.801 us; speedup 1.0000x reference)
//
#include <hip/hip_runtime.h>
#include <stdint.h>

typedef unsigned long long u64;

// Problem dims: B=512, N=100 -> M=51200 instances; T=100, L=50 conv positions,
// HE=64, E=128, NE=512, HD=256.

// ---------------- workspace layout (float offsets) ----------------
#define WS_ZBUF     0ll          // 51200*128
#define WS_ROWNORM  6553600ll    // 51200
#define WS_W2S      6604800ll    // 12288  (w2 as [ic][o][k])
#define WS_LATWT    6617088ll    // 8192   (lat_w^T [ic][e])
#define WS_D1T      6625280ll    // 32768  (d1_w^T [k][n])
#define WS_D2T      6658048ll    // 65536  (d2_w^T [k][n])
#define WS_D3T      6723584ll    // 25600  (d3_w^T [k][t])
#define WS_CBNORM   6749184ll    // 512
#define WS_ACCUMS   6749696ll    // 8: [0]=recon_acc [1]=vq_acc [2]=S_rw [3]=S_im
#define WS_GBEST    6749704ll    // 51200 u64 (byte offset %8==0)
#define WS_H1       6852608ll    // 51200*256
#define WS_H2       19959808ll   // 51200*256
// end = 33,067,008 floats = 132.3 MB

// ---------------- prep: weight transposes + codebook norms ----------------
__global__ __launch_bounds__(256) void prep_kernel(
    const float* __restrict__ w2, const float* __restrict__ latw,
    const float* __restrict__ d1w, const float* __restrict__ d2w,
    const float* __restrict__ d3w, const float* __restrict__ cb,
    float* __restrict__ w2s, float* __restrict__ latwt,
    float* __restrict__ d1t, float* __restrict__ d2t,
    float* __restrict__ d3t, float* __restrict__ cbnorm)
{
  const int total = 12288 + 8192 + 32768 + 65536 + 25600 + 512;
  for (int i = blockIdx.x*256 + threadIdx.x; i < total; i += gridDim.x*256) {
    int idx = i;
    if (idx < 12288) { // w2s[(ic*64+o)*3+k] = w2[(o*64+ic)*3+k]
      int k = idx % 3; int r = idx / 3; int o = r & 63; int ic = r >> 6;
      w2s[idx] = w2[(o*64 + ic)*3 + k]; continue;
    }
    idx -= 12288;
    if (idx < 8192) { int e = idx & 127; int ic = idx >> 7; latwt[idx] = latw[e*64 + ic]; continue; }
    idx -= 8192;
    if (idx < 32768) { int n = idx & 255; int k = idx >> 8; d1t[idx] = d1w[n*128 + k]; continue; }
    idx -= 32768;
    if (idx < 65536) { int n = idx & 255; int k = idx >> 8; d2t[idx] = d2w[n*256 + k]; continue; }
    idx -= 65536;
    if (idx < 25600) { int n = idx % 100; int k = idx / 100; d3t[idx] = d3w[n*256 + k]; continue; }
    idx -= 25600;
    { // codebook squared norms (f64 accumulate -> correctly rounded f32)
      double s = 0.0; const float* c = cb + idx*128;
      for (int e = 0; e < 128; ++e) { double v = (double)c[e]; s += v*v; }
      cbnorm[idx] = (float)s;
    }
  }
}

// ---------------- mask sums ----------------
__global__ __launch_bounds__(256) void masksum_kernel(
    const float* __restrict__ imask, const float* __restrict__ tm,
    float* __restrict__ accums)
{
  float rw = 0.f, si = 0.f;
  const int total = 51200*100;
  for (int i = blockIdx.x*256 + threadIdx.x; i < total; i += gridDim.x*256) {
    int m = i / 100;
    rw += imask[m] * tm[i];
    if (i < 51200) si += imask[i];   // stride > 51200 so each hit exactly once
  }
  #pragma unroll
  for (int off = 32; off > 0; off >>= 1) { rw += __shfl_down(rw, off); si += __shfl_down(si, off); }
  __shared__ float s_rw[4], s_si[4];
  int wid = threadIdx.x >> 6, lane = threadIdx.x & 63;
  if (lane == 0) { s_rw[wid] = rw; s_si[wid] = si; }
  __syncthreads();
  if (threadIdx.x == 0) {
    atomicAdd(&accums[2], s_rw[0]+s_rw[1]+s_rw[2]+s_rw[3]);
    atomicAdd(&accums[3], s_si[0]+s_si[1]+s_si[2]+s_si[3]);
  }
}

// ---------------- encoder: conv1 -> conv2 -> mean -> latent ----------------
// One block per instance. 4 waves; each wave owns 16 output channels; lanes = position l.
// conv2 weights are wave-uniform -> SGPR s_loads; only 3 ds_read per 48 FMAs.
__global__ __launch_bounds__(256) void encoder_kernel(
    const float* __restrict__ x, const float* __restrict__ tm,
    const float* __restrict__ imask,
    const float* __restrict__ w1, const float* __restrict__ b1,
    const float* __restrict__ w2s, const float* __restrict__ b2,
    const float* __restrict__ latwt, const float* __restrict__ latb,
    float* __restrict__ zbuf, float* __restrict__ rownorm)
{
  __shared__ float s_h0[2*52];    // 2 channels, halo'd length 52
  __shared__ float s_h1[64*52];   // conv1 output, halo'd
  __shared__ float s_hm[64];
  __shared__ float s_z[128];
  __shared__ float s_imv;
  const int m = blockIdx.x;
  const int tid = threadIdx.x;
  if (tid == 0) s_imv = imask[m];
  if (tid < 2)  { s_h0[tid*52] = 0.f; s_h0[tid*52 + 51] = 0.f; }
  if (tid < 64) { s_h1[tid*52] = 0.f; s_h1[tid*52 + 51] = 0.f; }
  __syncthreads();
  const float imv = s_imv;
  if (tid < 100) {
    float xv = x[m*100 + tid] * tm[m*100 + tid] * imv;
    // reshape (50,2) then transpose -> channel c = tid&1, pos l = tid>>1
    s_h0[(tid & 1)*52 + 1 + (tid >> 1)] = xv;
  }
  __syncthreads();

  const int lane = tid & 63;
  const int o0 = __builtin_amdgcn_readfirstlane((int)(tid >> 6)) * 16;
  const int ll = (lane < 50) ? lane : 0;

  // conv1 (cross-correlation, SAME pad): in[c][l+k-1] == s_h0[c][l+k]
  {
    const float a0 = s_h0[ll],    a1 = s_h0[ll+1],    a2 = s_h0[ll+2];
    const float c0 = s_h0[52+ll], c1 = s_h0[52+ll+1], c2 = s_h0[52+ll+2];
    #pragma unroll
    for (int oo = 0; oo < 16; ++oo) {
      const int o = o0 + oo;
      const float* __restrict__ w = w1 + o*6;
      float acc = b1[o];
      acc = fmaf(w[0], a0, acc); acc = fmaf(w[1], a1, acc); acc = fmaf(w[2], a2, acc);
      acc = fmaf(w[3], c0, acc); acc = fmaf(w[4], c1, acc); acc = fmaf(w[5], c2, acc);
      acc = fmaxf(acc, 0.f);
      if (lane < 50) s_h1[o*52 + 1 + lane] = acc;
    }
  }
  __syncthreads();

  // conv2: acc[oo] over 64 input channels x 3 taps
  float acc[16];
  #pragma unroll
  for (int oo = 0; oo < 16; ++oo) acc[oo] = 0.f;
  for (int ic = 0; ic < 64; ++ic) {
    const float hm  = s_h1[ic*52 + ll];
    const float h0v = s_h1[ic*52 + ll + 1];
    const float hp  = s_h1[ic*52 + ll + 2];
    const float* __restrict__ w = w2s + (ic*64 + o0)*3;  // wave-uniform -> s_load
    #pragma unroll
    for (int oo = 0; oo < 16; ++oo) {
      acc[oo] = fmaf(w[oo*3+0], hm,  acc[oo]);
      acc[oo] = fmaf(w[oo*3+1], h0v, acc[oo]);
      acc[oo] = fmaf(w[oo*3+2], hp,  acc[oo]);
    }
  }
  // relu + mean over 50 positions (wave reduce; idle lanes contribute 0)
  #pragma unroll
  for (int oo = 0; oo < 16; ++oo) {
    float v = fmaxf(acc[oo] + b2[o0+oo], 0.f);
    if (lane >= 50) v = 0.f;
    #pragma unroll
    for (int off = 32; off > 0; off >>= 1) v += __shfl_down(v, off);
    if (lane == 0) s_hm[o0+oo] = v / 50.0f;
  }
  __syncthreads();

  // latent: z[e] = lat_b[e] + sum_ic hm[ic]*lat_w[e][ic], masked
  if (tid < 128) {
    float a = latb[tid];
    #pragma unroll 8
    for (int ic = 0; ic < 64; ++ic) a = fmaf(s_hm[ic], latwt[ic*128 + tid], a);
    a *= imv;
    s_z[tid] = a;
    zbuf[m*128 + tid] = a;
  }
  __syncthreads();
  if (tid < 64) {
    float v = s_z[tid]*s_z[tid] + s_z[tid+64]*s_z[tid+64];
    #pragma unroll
    for (int off = 32; off > 0; off >>= 1) v += __shfl_down(v, off);
    if (tid == 0) rownorm[m] = v;
  }
}

// ---------------- VQ: distances + fused argmin ----------------
// 64 rows x 64 codes per block, K=128. d = fma(-2,p,A) + n  (mimics np formula).
__global__ __launch_bounds__(256) void vq_kernel(
    const float* __restrict__ zbuf, const float* __restrict__ cb,
    const float* __restrict__ rownorm, const float* __restrict__ cbnorm,
    u64* __restrict__ gbest)
{
  __shared__ float s_z[64*132];
  __shared__ float s_c[128*67];
  __shared__ u64 s_best[64];
  const int tid = threadIdx.x;
  const int m0 = blockIdx.x * 64;
  const int c0 = blockIdx.y * 64;
  {
    const int k = tid & 127, r2 = tid >> 7;
    #pragma unroll 4
    for (int p = 0; p < 32; ++p) {
      const int r = r2 + p*2;
      s_z[r*132 + k] = zbuf[(m0 + r)*128 + k];
      s_c[k*67 + r]  = cb[(c0 + r)*128 + k];
    }
  }
  if (tid < 64) s_best[tid] = ~0ULL;
  __syncthreads();
  const int rg = tid >> 4, cg = tid & 15;
  const int r0 = rg*4, j0 = cg*4;
  float accv[16];
  #pragma unroll
  for (int q = 0; q < 16; ++q) accv[q] = 0.f;
  #pragma unroll 4
  for (int k = 0; k < 128; ++k) {
    const float a0 = s_z[(r0+0)*132 + k];
    const float a1 = s_z[(r0+1)*132 + k];
    const float a2 = s_z[(r0+2)*132 + k];
    const float a3 = s_z[(r0+3)*132 + k];
    const float b0 = s_c[k*67 + j0+0];
    const float b1 = s_c[k*67 + j0+1];
    const float b2 = s_c[k*67 + j0+2];
    const float b3 = s_c[k*67 + j0+3];
    accv[0]=fmaf(a0,b0,accv[0]);  accv[1]=fmaf(a0,b1,accv[1]);
    accv[2]=fmaf(a0,b2,accv[2]);  accv[3]=fmaf(a0,b3,accv[3]);
    accv[4]=fmaf(a1,b0,accv[4]);  accv[5]=fmaf(a1,b1,accv[5]);
    accv[6]=fmaf(a1,b2,accv[6]);  accv[7]=fmaf(a1,b3,accv[7]);
    accv[8]=fmaf(a2,b0,accv[8]);  accv[9]=fmaf(a2,b1,accv[9]);
    accv[10]=fmaf(a2,b2,accv[10]); accv[11]=fmaf(a2,b3,accv[11]);
    accv[12]=fmaf(a3,b0,accv[12]); accv[13]=fmaf(a3,b1,accv[13]);
    accv[14]=fmaf(a3,b2,accv[14]); accv[15]=fmaf(a3,b3,accv[15]);
  }
  #pragma unroll
  for (int i = 0; i < 4; ++i) {
    const float A = rownorm[m0 + r0 + i];
    u64 best = ~0ULL;
    #pragma unroll
    for (int j = 0; j < 4; ++j) {
      const float t = fmaf(-2.0f, accv[i*4+j], A);   // == round(A - 2p), matches np
      const float d = t + cbnorm[c0 + j0 + j];
      const u64 pk = ((u64)__float_as_uint(d) << 32) | (u64)(unsigned)(c0 + j0 + j);
      best = (pk < best) ? pk : best;   // tie -> lowest index (np first-occurrence)
    }
    atomicMin(&s_best[r0 + i], best);
  }
  __syncthreads();
  if (tid < 64) atomicMin(&gbest[m0 + tid], s_best[tid]);
}

// ---------------- indices output + vq loss ----------------
__global__ __launch_bounds__(256) void vqloss_kernel(
    const float* __restrict__ zbuf, const float* __restrict__ cb,
    const float* __restrict__ imask, const u64* __restrict__ gbest,
    float* __restrict__ out_idx, float* __restrict__ accums)
{
  const int wid = threadIdx.x >> 6, lane = threadIdx.x & 63;
  const int gw = blockIdx.x*4 + wid;
  const int nw = gridDim.x*4;
  float vqp = 0.f;
  for (int r = gw; r < 51200; r += nw) {
    const int idx = (int)(unsigned)(gbest[r] & 0xffffffffULL);
    const float imv = imask[r];
    const float* z = zbuf + (long)r*128;
    const float* c = cb + (long)idx*128;
    const float d0 = z[lane]    - c[lane];
    const float d1 = z[lane+64] - c[lane+64];
    float v = d0*d0 + d1*d1;
    #pragma unroll
    for (int off = 32; off > 0; off >>= 1) v += __shfl_down(v, off);
    if (lane == 0) {
      out_idx[r] = (imv > 0.f) ? (float)idx : -1.0f;
      vqp += 1.25f * (v * (1.0f/128.0f)) * imv;   // (BETA+1)*mean
    }
  }
  __shared__ float s_p[4];
  if (lane == 0) s_p[wid] = vqp;
  __syncthreads();
  if (threadIdx.x == 0) atomicAdd(&accums[1], s_p[0]+s_p[1]+s_p[2]+s_p[3]);
}

// ---------------- decoder GEMM 1: h1 = relu(zq_masked @ d1_w^T + b) ----------------
__global__ __launch_bounds__(256) void dec1_kernel(
    const float* __restrict__ cb, const u64* __restrict__ gbest,
    const float* __restrict__ imask, const float* __restrict__ bt,
    const float* __restrict__ bias, float* __restrict__ outbuf)
{
  __shared__ float s_a[64*33];
  __shared__ float s_b[32*65];
  __shared__ int   s_idx[64];
  __shared__ float s_act[64];
  const int tid = threadIdx.x;
  const int m0 = blockIdx.x*64, n0 = blockIdx.y*64;
  if (tid < 64) {
    s_idx[tid] = (int)(unsigned)(gbest[m0+tid] & 0xffffffffULL);
    s_act[tid] = imask[m0+tid];
  }
  float acc[16];
  #pragma unroll
  for (int q = 0; q < 16; ++q) acc[q] = 0.f;
  const int rg = tid >> 4, cg = tid & 15;
  for (int k0 = 0; k0 < 128; k0 += 32) {
    __syncthreads();
    {
      const int k = tid & 31, r8 = tid >> 5;
      #pragma unroll
      for (int p = 0; p < 8; ++p) {
        const int r = r8 + p*8;
        s_a[r*33 + k] = cb[(long)s_idx[r]*128 + k0 + k] * s_act[r];
      }
      const int n = tid & 63, kk = tid >> 6;
      #pragma unroll
      for (int p = 0; p < 8; ++p) {
        const int kr = kk + p*4;
        s_b[kr*65 + n] = bt[(k0+kr)*256 + n0 + n];
      }
    }
    __syncthreads();
    #pragma unroll 8
    for (int k = 0; k < 32; ++k) {
      const float a0 = s_a[(rg*4+0)*33 + k], a1 = s_a[(rg*4+1)*33 + k],
                  a2 = s_a[(rg*4+2)*33 + k], a3 = s_a[(rg*4+3)*33 + k];
      const float b0 = s_b[k*65 + cg*4+0], b1 = s_b[k*65 + cg*4+1],
                  b2 = s_b[k*65 + cg*4+2], b3 = s_b[k*65 + cg*4+3];
      acc[0]=fmaf(a0,b0,acc[0]);  acc[1]=fmaf(a0,b1,acc[1]);
      acc[2]=fmaf(a0,b2,acc[2]);  acc[3]=fmaf(a0,b3,acc[3]);
      acc[4]=fmaf(a1,b0,acc[4]);  acc[5]=fmaf(a1,b1,acc[5]);
      acc[6]=fmaf(a1,b2,acc[6]);  acc[7]=fmaf(a1,b3,acc[7]);
      acc[8]=fmaf(a2,b0,acc[8]);  acc[9]=fmaf(a2,b1,acc[9]);
      acc[10]=fmaf(a2,b2,acc[10]); acc[11]=fmaf(a2,b3,acc[11]);
      acc[12]=fmaf(a3,b0,acc[12]); acc[13]=fmaf(a3,b1,acc[13]);
      acc[14]=fmaf(a3,b2,acc[14]); acc[15]=fmaf(a3,b3,acc[15]);
    }
  }
  #pragma unroll
  for (int i = 0; i < 4; ++i) {
    const int r = m0 + rg*4 + i;
    #pragma unroll
    for (int j = 0; j < 4; ++j) {
      const int n = n0 + cg*4 + j;
      outbuf[(long)r*256 + n] = fmaxf(acc[i*4+j] + bias[n], 0.f);
    }
  }
}

// ---------------- decoder GEMM 2: h2 = relu(h1 @ d2_w^T + b), K=256 ----------------
__global__ __launch_bounds__(256) void dec2_kernel(
    const float* __restrict__ ain, const float* __restrict__ bt,
    const float* __restrict__ bias, float* __restrict__ outbuf)
{
  __shared__ float s_a[64*33];
  __shared__ float s_b[32*65];
  const int tid = threadIdx.x;
  const int m0 = blockIdx.x*64, n0 = blockIdx.y*64;
  float acc[16];
  #pragma unroll
  for (int q = 0; q < 16; ++q) acc[q] = 0.f;
  const int rg = tid >> 4, cg = tid & 15;
  for (int k0 = 0; k0 < 256; k0 += 32) {
    __syncthreads();
    {
      const int k = tid & 31, r8 = tid >> 5;
      #pragma unroll
      for (int p = 0; p < 8; ++p) {
        const int r = r8 + p*8;
        s_a[r*33 + k] = ain[(long)(m0+r)*256 + k0 + k];
      }
      const int n = tid & 63, kk = tid >> 6;
      #pragma unroll
      for (int p = 0; p < 8; ++p) {
        const int kr = kk + p*4;
        s_b[kr*65 + n] = bt[(k0+kr)*256 + n0 + n];
      }
    }
    __syncthreads();
    #pragma unroll 8
    for (int k = 0; k < 32; ++k) {
      const float a0 = s_a[(rg*4+0)*33 + k], a1 = s_a[(rg*4+1)*33 + k],
                  a2 = s_a[(rg*4+2)*33 + k], a3 = s_a[(rg*4+3)*33 + k];
      const float b0 = s_b[k*65 + cg*4+0], b1 = s_b[k*65 + cg*4+1],
                  b2 = s_b[k*65 + cg*4+2], b3 = s_b[k*65 + cg*4+3];
      acc[0]=fmaf(a0,b0,acc[0]);  acc[1]=fmaf(a0,b1,acc[1]);
      acc[2]=fmaf(a0,b2,acc[2]);  acc[3]=fmaf(a0,b3,acc[3]);
      acc[4]=fmaf(a1,b0,acc[4]);  acc[5]=fmaf(a1,b1,acc[5]);
      acc[6]=fmaf(a1,b2,acc[6]);  acc[7]=fmaf(a1,b3,acc[7]);
      acc[8]=fmaf(a2,b0,acc[8]);  acc[9]=fmaf(a2,b1,acc[9]);
      acc[10]=fmaf(a2,b2,acc[10]); acc[11]=fmaf(a2,b3,acc[11]);
      acc[12]=fmaf(a3,b0,acc[12]); acc[13]=fmaf(a3,b1,acc[13]);
      acc[14]=fmaf(a3,b2,acc[14]); acc[15]=fmaf(a3,b3,acc[15]);
    }
  }
  #pragma unroll
  for (int i = 0; i < 4; ++i) {
    const int r = m0 + rg*4 + i;
    #pragma unroll
    for (int j = 0; j < 4; ++j) {
      const int n = n0 + cg*4 + j;
      outbuf[(long)r*256 + n] = fmaxf(acc[i*4+j] + bias[n], 0.f);
    }
  }
}

// ---------------- decoder GEMM 3: x_hat = h2 @ d3_w^T + b (N=100) + recon loss ----------------
__global__ __launch_bounds__(256) void dec3_kernel(
    const float* __restrict__ ain, const float* __restrict__ bt,
    const float* __restrict__ bias, const float* __restrict__ x,
    const float* __restrict__ tm, const float* __restrict__ imask,
    float* __restrict__ xhat, float* __restrict__ accums)
{
  __shared__ float s_a[64*33];
  __shared__ float s_b[32*65];
  const int tid = threadIdx.x;
  const int m0 = blockIdx.x*64, n0 = blockIdx.y*64;
  float acc[16];
  #pragma unroll
  for (int q = 0; q < 16; ++q) acc[q] = 0.f;
  const int rg = tid >> 4, cg = tid & 15;
  for (int k0 = 0; k0 < 256; k0 += 32) {
    __syncthreads();
    {
      const int k = tid & 31, r8 = tid >> 5;
      #pragma unroll
      for (int p = 0; p < 8; ++p) {
        const int r = r8 + p*8;
        s_a[r*33 + k] = ain[(long)(m0+r)*256 + k0 + k];
      }
      const int n = tid & 63, kk = tid >> 6;
      #pragma unroll
      for (int p = 0; p < 8; ++p) {
        const int kr = kk + p*4;
        const int col = n0 + n;
        s_b[kr*65 + n] = (col < 100) ? bt[(k0+kr)*100 + col] : 0.f;
      }
    }
    __syncthreads();
    #pragma unroll 8
    for (int k = 0; k < 32; ++k) {
      const float a0 = s_a[(rg*4+0)*33 + k], a1 = s_a[(rg*4+1)*33 + k],
                  a2 = s_a[(rg*4+2)*33 + k], a3 = s_a[(rg*4+3)*33 + k];
      const float b0 = s_b[k*65 + cg*4+0], b1 = s_b[k*65 + cg*4+1],
                  b2 = s_b[k*65 + cg*4+2], b3 = s_b[k*65 + cg*4+3];
      acc[0]=fmaf(a0,b0,acc[0]);  acc[1]=fmaf(a0,b1,acc[1]);
      acc[2]=fmaf(a0,b2,acc[2]);  acc[3]=fmaf(a0,b3,acc[3]);
      acc[4]=fmaf(a1,b0,acc[4]);  acc[5]=fmaf(a1,b1,acc[5]);
      acc[6]=fmaf(a1,b2,acc[6]);  acc[7]=fmaf(a1,b3,acc[7]);
      acc[8]=fmaf(a2,b0,acc[8]);  acc[9]=fmaf(a2,b1,acc[9]);
      acc[10]=fmaf(a2,b2,acc[10]); acc[11]=fmaf(a2,b3,acc[11]);
      acc[12]=fmaf(a3,b0,acc[12]); acc[13]=fmaf(a3,b1,acc[13]);
      acc[14]=fmaf(a3,b2,acc[14]); acc[15]=fmaf(a3,b3,acc[15]);
    }
  }
  float part = 0.f;
  #pragma unroll
  for (int i = 0; i < 4; ++i) {
    const int r = m0 + rg*4 + i;
    const float imv = imask[r];
    #pragma unroll
    for (int j = 0; j < 4; ++j) {
      const int col = n0 + cg*4 + j;
      if (col < 100) {
        const float xh = acc[i*4+j] + bias[col];
        xhat[(long)r*100 + col] = xh;
        const float wgt = imv * tm[(long)r*100 + col];
        const float df = xh - x[(long)r*100 + col];
        part = fmaf(df*df, wgt, part);
      }
    }
  }
  #pragma unroll
  for (int off = 32; off > 0; off >>= 1) part += __shfl_down(part, off);
  __shared__ float s_p[4];
  const int wid = tid >> 6, lane = tid & 63;
  if (lane == 0) s_p[wid] = part;
  __syncthreads();
  if (tid == 0) atomicAdd(&accums[0], s_p[0]+s_p[1]+s_p[2]+s_p[3]);
}

// ---------------- finalize scalars ----------------
__global__ void finalize_kernel(const float* __restrict__ accums, float* __restrict__ out) {
  if (threadIdx.x == 0 && blockIdx.x == 0) {
    out[5120000] = accums[0] / fmaxf(accums[2], 1.0f);
    out[5120001] = accums[1] / fmaxf(accums[3], 1.0f);
  }
}

extern "C" void kernel_launch(void* const* d_in, const int* in_sizes, int n_in,
                              void* d_out, int out_size, void* d_ws, size_t ws_size,
                              hipStream_t stream)
{
  (void)in_sizes; (void)n_in; (void)out_size; (void)ws_size;
  const float* x     = (const float*)d_in[0];
  const float* tmsk  = (const float*)d_in[1];
  const float* imask = (const float*)d_in[2];
  const float* w1    = (const float*)d_in[3];
  const float* b1    = (const float*)d_in[4];
  const float* w2    = (const float*)d_in[5];
  const float* b2    = (const float*)d_in[6];
  const float* latw  = (const float*)d_in[7];
  const float* latb  = (const float*)d_in[8];
  const float* cb    = (const float*)d_in[9];
  const float* d1w   = (const float*)d_in[10];
  const float* d1b   = (const float*)d_in[11];
  const float* d2w   = (const float*)d_in[12];
  const float* d2b   = (const float*)d_in[13];
  const float* d3w   = (const float*)d_in[14];
  const float* d3b   = (const float*)d_in[15];
  float* out = (float*)d_out;
  float* ws  = (float*)d_ws;

  float* zbuf    = ws + WS_ZBUF;
  float* rown    = ws + WS_ROWNORM;
  float* w2s     = ws + WS_W2S;
  float* latwt   = ws + WS_LATWT;
  float* d1t     = ws + WS_D1T;
  float* d2t     = ws + WS_D2T;
  float* d3t     = ws + WS_D3T;
  float* cbnorm  = ws + WS_CBNORM;
  float* accums  = ws + WS_ACCUMS;
  u64*   gbest   = (u64*)(ws + WS_GBEST);
  float* h1      = ws + WS_H1;
  float* h2      = ws + WS_H2;
  float* xhat    = out;
  float* out_idx = out + 5120002;

  hipMemsetAsync(gbest, 0xFF, 51200*sizeof(u64), stream);   // +inf sentinel
  hipMemsetAsync(accums, 0, 8*sizeof(float), stream);

  prep_kernel<<<512, 256, 0, stream>>>(w2, latw, d1w, d2w, d3w, cb,
                                       w2s, latwt, d1t, d2t, d3t, cbnorm);
  masksum_kernel<<<1024, 256, 0, stream>>>(imask, tmsk, accums);
  encoder_kernel<<<51200, 256, 0, stream>>>(x, tmsk, imask, w1, b1, w2s, b2,
                                            latwt, latb, zbuf, rown);
  vq_kernel<<<dim3(800, 8), 256, 0, stream>>>(zbuf, cb, rown, cbnorm, gbest);
  vqloss_kernel<<<256, 256, 0, stream>>>(zbuf, cb, imask, gbest, out_idx, accums);
  dec1_kernel<<<dim3(800, 4), 256, 0, stream>>>(cb, gbest, imask, d1t, d1b, h1);
  dec2_kernel<<<dim3(800, 4), 256, 0, stream>>>(h1, d2t, d2b, h2);
  dec3_kernel<<<dim3(800, 2), 256, 0, stream>>>(h2, d3t, d3b, x, tmsk, imask, xhat, accums);
  finalize_kernel<<<1, 64, 0, stream>>>(accums, out);
}

// Round 2
// 1006.200 us; speedup vs baseline: 1.8881x; 1.8881x over previous
//
#include <hip/hip_runtime.h>
#include <stdint.h>

typedef unsigned long long u64;
typedef unsigned short ushort_t;
typedef __attribute__((ext_vector_type(8))) short short8;
typedef __attribute__((ext_vector_type(16))) float f32x16;

// Problem dims: B=512, N=100 -> M=51200 instances; T=100, L=50 conv positions,
// HE=64, E=128, NE=512, HD=256.

// ---------------- workspace layout (float offsets) ----------------
#define WS_ZBUF     0ll          // 51200*128
#define WS_ROWNORM  6553600ll    // 51200
#define WS_BFRAG    6604800ll    // 12288 floats = bhi[12288]+blo[12288] ushorts
#define WS_LATWT    6617088ll    // 8192   (lat_w^T [ic][e])
#define WS_D1T      6625280ll    // 32768  (d1_w^T [k][n])
#define WS_D2T      6658048ll    // 65536  (d2_w^T [k][n])
#define WS_D3T      6723584ll    // 25600  (d3_w^T [k][t])
#define WS_CBNORM   6749184ll    // 512
#define WS_ACCUMS   6749696ll    // 8: [0]=recon_acc [1]=vq_acc [2]=S_rw [3]=S_im
#define WS_GBEST    6749704ll    // 51200 u64 (byte offset %8==0)
#define WS_H1       6852608ll    // 51200*256
#define WS_H2       19959808ll   // 51200*256

// round-to-nearest-even f32 -> bf16 bits
__device__ __host__ inline ushort_t bf16_rn(float v) {
  unsigned u = __float_as_uint(v);
  unsigned r = (u + 0x7fffu + ((u >> 16) & 1u)) >> 16;
  return (ushort_t)r;
}

// ---------------- prep: weight frag-pack + transposes + codebook norms ----------------
__global__ __launch_bounds__(256) void prep_kernel(
    const float* __restrict__ w2, const float* __restrict__ latw,
    const float* __restrict__ d1w, const float* __restrict__ d2w,
    const float* __restrict__ d3w, const float* __restrict__ cb,
    ushort_t* __restrict__ bhi, ushort_t* __restrict__ blo,
    float* __restrict__ latwt,
    float* __restrict__ d1t, float* __restrict__ d2t,
    float* __restrict__ d3t, float* __restrict__ cbnorm)
{
  const int total = 12288 + 8192 + 32768 + 65536 + 25600 + 512;
  for (int i = blockIdx.x*256 + threadIdx.x; i < total; i += gridDim.x*256) {
    int idx = i;
    if (idx < 12288) {
      // MFMA 32x32x16 B-fragment order: frag f = ((t*2+nt)*4+kt), lane, j
      // element B[k = kt*16 + (lane>>5)*8 + j][n = nt*32 + (lane&31)] = w2[oc][ic][t]
      int j = idx & 7, l6 = (idx >> 3) & 63, f = idx >> 9;
      int kt = f & 3, ntt = (f >> 2) & 1, t = f >> 3;
      int oc = ntt*32 + (l6 & 31);
      int ic = kt*16 + (l6 >> 5)*8 + j;
      float v = w2[(oc*64 + ic)*3 + t];
      ushort_t hi = bf16_rn(v);
      float hf = __uint_as_float(((unsigned)hi) << 16);
      ushort_t lo = bf16_rn(v - hf);
      bhi[idx] = hi; blo[idx] = lo; continue;
    }
    idx -= 12288;
    if (idx < 8192) { int e = idx & 127; int ic = idx >> 7; latwt[idx] = latw[e*64 + ic]; continue; }
    idx -= 8192;
    if (idx < 32768) { int n = idx & 255; int k = idx >> 8; d1t[idx] = d1w[n*128 + k]; continue; }
    idx -= 32768;
    if (idx < 65536) { int n = idx & 255; int k = idx >> 8; d2t[idx] = d2w[n*256 + k]; continue; }
    idx -= 65536;
    if (idx < 25600) { int n = idx % 100; int k = idx / 100; d3t[idx] = d3w[n*256 + k]; continue; }
    idx -= 25600;
    { // codebook squared norms (f64 accumulate -> correctly rounded f32)
      double s = 0.0; const float* c = cb + idx*128;
      for (int e = 0; e < 128; ++e) { double v = (double)c[e]; s += v*v; }
      cbnorm[idx] = (float)s;
    }
  }
}

// ---------------- mask sums ----------------
__global__ __launch_bounds__(256) void masksum_kernel(
    const float* __restrict__ imask, const float* __restrict__ tm,
    float* __restrict__ accums)
{
  float rw = 0.f, si = 0.f;
  const int total = 51200*100;
  for (int i = blockIdx.x*256 + threadIdx.x; i < total; i += gridDim.x*256) {
    int m = i / 100;
    rw += imask[m] * tm[i];
    if (i < 51200) si += imask[i];
  }
  #pragma unroll
  for (int off = 32; off > 0; off >>= 1) { rw += __shfl_down(rw, off); si += __shfl_down(si, off); }
  __shared__ float s_rw[4], s_si[4];
  int wid = threadIdx.x >> 6, lane = threadIdx.x & 63;
  if (lane == 0) { s_rw[wid] = rw; s_si[wid] = si; }
  __syncthreads();
  if (threadIdx.x == 0) {
    atomicAdd(&accums[2], s_rw[0]+s_rw[1]+s_rw[2]+s_rw[3]);
    atomicAdd(&accums[3], s_si[0]+s_si[1]+s_si[2]+s_si[3]);
  }
}

// ---------------- encoder: conv1 (f32) -> conv2 (bf16-split MFMA) -> mean -> latent ----------------
// One block per instance, 4 waves = (mt,nt) tile of the 64x64 (pos x oc) conv2 output.
// conv2 = 3 tap-shifted GEMMs, K=64(ic), via v_mfma_f32_32x32x16_bf16, 3-pass hi/lo split.
__global__ __launch_bounds__(256) void encoder_kernel(
    const float* __restrict__ x, const float* __restrict__ tm,
    const float* __restrict__ imask,
    const float* __restrict__ w1, const float* __restrict__ b1,
    const ushort_t* __restrict__ bhi, const ushort_t* __restrict__ blo,
    const float* __restrict__ b2,
    const float* __restrict__ latwt, const float* __restrict__ latb,
    float* __restrict__ zbuf, float* __restrict__ rownorm)
{
  __shared__ float s_h0[2*52];          // 2 channels, halo'd length 52
  __shared__ ushort_t s_Hhi[52*68];     // conv1 out bf16-hi: row = pos+1 (rows 0,51 = zero pad), col = ic
  __shared__ ushort_t s_Hlo[52*68];     // conv1 out bf16-lo
  __shared__ float s_red[2][64];
  __shared__ float s_hm[64];
  __shared__ float s_z[128];
  __shared__ float s_imv;
  const int m = blockIdx.x;
  const int tid = threadIdx.x;
  if (tid == 0) s_imv = imask[m];
  if (tid < 2)  { s_h0[tid*52] = 0.f; s_h0[tid*52 + 51] = 0.f; }
  if (tid < 68) {
    s_Hhi[tid] = 0; s_Hlo[tid] = 0;
    s_Hhi[51*68 + tid] = 0; s_Hlo[51*68 + tid] = 0;
  }
  __syncthreads();
  const float imv = s_imv;
  if (tid < 100) {
    float xv = x[m*100 + tid] * tm[m*100 + tid] * imv;
    s_h0[(tid & 1)*52 + 1 + (tid >> 1)] = xv;   // channel c = tid&1, pos l = tid>>1
  }
  __syncthreads();

  const int wv   = __builtin_amdgcn_readfirstlane((int)(tid >> 6));
  const int lane = tid & 63;
  const int ln31 = lane & 31, half = lane >> 5;
  const int mt = wv >> 1, nt = wv & 1;

  // ---- B fragments (weights), preloaded from frag-packed global (L1/L2-hot) ----
  short8 Bh[12], Bl[12];
  {
    const short8* bh8 = (const short8*)bhi;
    const short8* bl8 = (const short8*)blo;
    #pragma unroll
    for (int t = 0; t < 3; ++t)
      #pragma unroll
      for (int kt = 0; kt < 4; ++kt) {
        const int f = ((t*2 + nt)*4 + kt);
        Bh[t*4+kt] = bh8[f*64 + lane];
        Bl[t*4+kt] = bl8[f*64 + lane];
      }
  }

  // ---- conv1 (f32) + bf16 hi/lo split into LDS ----
  {
    const int o0 = wv*16;
    const int ll = (lane < 50) ? lane : 0;
    const float a0 = s_h0[ll],    a1 = s_h0[ll+1],    a2 = s_h0[ll+2];
    const float c0 = s_h0[52+ll], c1 = s_h0[52+ll+1], c2 = s_h0[52+ll+2];
    #pragma unroll
    for (int oo = 0; oo < 16; ++oo) {
      const int o = o0 + oo;
      const float* __restrict__ w = w1 + o*6;
      float h = b1[o];
      h = fmaf(w[0], a0, h); h = fmaf(w[1], a1, h); h = fmaf(w[2], a2, h);
      h = fmaf(w[3], c0, h); h = fmaf(w[4], c1, h); h = fmaf(w[5], c2, h);
      h = fmaxf(h, 0.f);
      if (lane >= 50) h = 0.f;
      const ushort_t hhi = bf16_rn(h);
      const float hf = __uint_as_float(((unsigned)hhi) << 16);
      const ushort_t hlo = bf16_rn(h - hf);
      if (lane < 51) {
        s_Hhi[(lane+1)*68 + o] = hhi;
        s_Hlo[(lane+1)*68 + o] = hlo;
      }
    }
  }
  __syncthreads();

  // ---- conv2 MFMA: acc[M=pos 32-tile][N=oc 32-tile], 3 taps x 4 k-tiles x 3 passes ----
  f32x16 acc;
  #pragma unroll
  for (int q = 0; q < 16; ++q) acc[q] = 0.f;
  #pragma unroll
  for (int t = 0; t < 3; ++t) {
    int rowA = mt*32 + ln31 + t;          // H row = m + t  (H row r = pos r-1)
    if (rowA > 51) rowA = 51;             // clamp to zero row (rows m>=50 are don't-care)
    const int rbase = rowA*68 + half*8;
    #pragma unroll
    for (int kt = 0; kt < 4; ++kt) {
      union { unsigned long long q[2]; short8 v; } ah, al;
      const unsigned long long* ph = (const unsigned long long*)(s_Hhi + rbase + kt*16);
      const unsigned long long* pl = (const unsigned long long*)(s_Hlo + rbase + kt*16);
      ah.q[0] = ph[0]; ah.q[1] = ph[1];
      al.q[0] = pl[0]; al.q[1] = pl[1];
      acc = __builtin_amdgcn_mfma_f32_32x32x16_bf16(ah.v, Bh[t*4+kt], acc, 0, 0, 0);
      acc = __builtin_amdgcn_mfma_f32_32x32x16_bf16(ah.v, Bl[t*4+kt], acc, 0, 0, 0);
      acc = __builtin_amdgcn_mfma_f32_32x32x16_bf16(al.v, Bh[t*4+kt], acc, 0, 0, 0);
    }
  }

  // ---- epilogue: relu(acc + b2) for pos<50, sum over pos, mean ----
  {
    const float bias = b2[nt*32 + ln31];
    float sum = 0.f;
    #pragma unroll
    for (int r = 0; r < 16; ++r) {
      // C/D layout: col = lane&31 (oc), row = (r&3) + 8*(r>>2) + 4*half (pos within tile)
      const int mpos = mt*32 + (r & 3) + 8*(r >> 2) + 4*half;
      const float v = fmaxf(acc[r] + bias, 0.f);
      if (mpos < 50) sum += v;
    }
    sum += __shfl_xor(sum, 32);
    if (half == 0) s_red[mt][nt*32 + ln31] = sum;
  }
  __syncthreads();
  if (tid < 64) s_hm[tid] = (s_red[0][tid] + s_red[1][tid]) * 0.02f;   // /50
  __syncthreads();

  // ---- latent (f32): z[e] = lat_b[e] + sum_ic hm[ic]*lat_w[e][ic], masked ----
  if (tid < 128) {
    float a = latb[tid];
    #pragma unroll 8
    for (int ic = 0; ic < 64; ++ic) a = fmaf(s_hm[ic], latwt[ic*128 + tid], a);
    a *= imv;
    s_z[tid] = a;
    zbuf[m*128 + tid] = a;
  }
  __syncthreads();
  if (tid < 64) {
    float v = s_z[tid]*s_z[tid] + s_z[tid+64]*s_z[tid+64];
    #pragma unroll
    for (int off = 32; off > 0; off >>= 1) v += __shfl_down(v, off);
    if (tid == 0) rownorm[m] = v;
  }
}

// ---------------- VQ: distances + fused argmin ----------------
__global__ __launch_bounds__(256) void vq_kernel(
    const float* __restrict__ zbuf, const float* __restrict__ cb,
    const float* __restrict__ rownorm, const float* __restrict__ cbnorm,
    u64* __restrict__ gbest)
{
  __shared__ float s_z[64*132];
  __shared__ float s_c[128*67];
  __shared__ u64 s_best[64];
  const int tid = threadIdx.x;
  const int m0 = blockIdx.x * 64;
  const int c0 = blockIdx.y * 64;
  {
    const int k = tid & 127, r2 = tid >> 7;
    #pragma unroll 4
    for (int p = 0; p < 32; ++p) {
      const int r = r2 + p*2;
      s_z[r*132 + k] = zbuf[(m0 + r)*128 + k];
      s_c[k*67 + r]  = cb[(c0 + r)*128 + k];
    }
  }
  if (tid < 64) s_best[tid] = ~0ULL;
  __syncthreads();
  const int rg = tid >> 4, cg = tid & 15;
  const int r0 = rg*4, j0 = cg*4;
  float accv[16];
  #pragma unroll
  for (int q = 0; q < 16; ++q) accv[q] = 0.f;
  #pragma unroll 4
  for (int k = 0; k < 128; ++k) {
    const float a0 = s_z[(r0+0)*132 + k];
    const float a1 = s_z[(r0+1)*132 + k];
    const float a2 = s_z[(r0+2)*132 + k];
    const float a3 = s_z[(r0+3)*132 + k];
    const float b0 = s_c[k*67 + j0+0];
    const float b1 = s_c[k*67 + j0+1];
    const float b2 = s_c[k*67 + j0+2];
    const float b3 = s_c[k*67 + j0+3];
    accv[0]=fmaf(a0,b0,accv[0]);  accv[1]=fmaf(a0,b1,accv[1]);
    accv[2]=fmaf(a0,b2,accv[2]);  accv[3]=fmaf(a0,b3,accv[3]);
    accv[4]=fmaf(a1,b0,accv[4]);  accv[5]=fmaf(a1,b1,accv[5]);
    accv[6]=fmaf(a1,b2,accv[6]);  accv[7]=fmaf(a1,b3,accv[7]);
    accv[8]=fmaf(a2,b0,accv[8]);  accv[9]=fmaf(a2,b1,accv[9]);
    accv[10]=fmaf(a2,b2,accv[10]); accv[11]=fmaf(a2,b3,accv[11]);
    accv[12]=fmaf(a3,b0,accv[12]); accv[13]=fmaf(a3,b1,accv[13]);
    accv[14]=fmaf(a3,b2,accv[14]); accv[15]=fmaf(a3,b3,accv[15]);
  }
  #pragma unroll
  for (int i = 0; i < 4; ++i) {
    const float A = rownorm[m0 + r0 + i];
    u64 best = ~0ULL;
    #pragma unroll
    for (int j = 0; j < 4; ++j) {
      const float t = fmaf(-2.0f, accv[i*4+j], A);
      const float d = t + cbnorm[c0 + j0 + j];
      const u64 pk = ((u64)__float_as_uint(d) << 32) | (u64)(unsigned)(c0 + j0 + j);
      best = (pk < best) ? pk : best;
    }
    atomicMin(&s_best[r0 + i], best);
  }
  __syncthreads();
  if (tid < 64) atomicMin(&gbest[m0 + tid], s_best[tid]);
}

// ---------------- indices output + vq loss ----------------
__global__ __launch_bounds__(256) void vqloss_kernel(
    const float* __restrict__ zbuf, const float* __restrict__ cb,
    const float* __restrict__ imask, const u64* __restrict__ gbest,
    float* __restrict__ out_idx, float* __restrict__ accums)
{
  const int wid = threadIdx.x >> 6, lane = threadIdx.x & 63;
  const int gw = blockIdx.x*4 + wid;
  const int nw = gridDim.x*4;
  float vqp = 0.f;
  for (int r = gw; r < 51200; r += nw) {
    const int idx = (int)(unsigned)(gbest[r] & 0xffffffffULL);
    const float imv = imask[r];
    const float* z = zbuf + (long)r*128;
    const float* c = cb + (long)idx*128;
    const float d0 = z[lane]    - c[lane];
    const float d1 = z[lane+64] - c[lane+64];
    float v = d0*d0 + d1*d1;
    #pragma unroll
    for (int off = 32; off > 0; off >>= 1) v += __shfl_down(v, off);
    if (lane == 0) {
      out_idx[r] = (imv > 0.f) ? (float)idx : -1.0f;
      vqp += 1.25f * (v * (1.0f/128.0f)) * imv;
    }
  }
  __shared__ float s_p[4];
  if (lane == 0) s_p[wid] = vqp;
  __syncthreads();
  if (threadIdx.x == 0) atomicAdd(&accums[1], s_p[0]+s_p[1]+s_p[2]+s_p[3]);
}

// ---------------- decoder GEMM 1 ----------------
__global__ __launch_bounds__(256) void dec1_kernel(
    const float* __restrict__ cb, const u64* __restrict__ gbest,
    const float* __restrict__ imask, const float* __restrict__ bt,
    const float* __restrict__ bias, float* __restrict__ outbuf)
{
  __shared__ float s_a[64*33];
  __shared__ float s_b[32*65];
  __shared__ int   s_idx[64];
  __shared__ float s_act[64];
  const int tid = threadIdx.x;
  const int m0 = blockIdx.x*64, n0 = blockIdx.y*64;
  if (tid < 64) {
    s_idx[tid] = (int)(unsigned)(gbest[m0+tid] & 0xffffffffULL);
    s_act[tid] = imask[m0+tid];
  }
  float acc[16];
  #pragma unroll
  for (int q = 0; q < 16; ++q) acc[q] = 0.f;
  const int rg = tid >> 4, cg = tid & 15;
  for (int k0 = 0; k0 < 128; k0 += 32) {
    __syncthreads();
    {
      const int k = tid & 31, r8 = tid >> 5;
      #pragma unroll
      for (int p = 0; p < 8; ++p) {
        const int r = r8 + p*8;
        s_a[r*33 + k] = cb[(long)s_idx[r]*128 + k0 + k] * s_act[r];
      }
      const int n = tid & 63, kk = tid >> 6;
      #pragma unroll
      for (int p = 0; p < 8; ++p) {
        const int kr = kk + p*4;
        s_b[kr*65 + n] = bt[(k0+kr)*256 + n0 + n];
      }
    }
    __syncthreads();
    #pragma unroll 8
    for (int k = 0; k < 32; ++k) {
      const float a0 = s_a[(rg*4+0)*33 + k], a1 = s_a[(rg*4+1)*33 + k],
                  a2 = s_a[(rg*4+2)*33 + k], a3 = s_a[(rg*4+3)*33 + k];
      const float b0 = s_b[k*65 + cg*4+0], b1 = s_b[k*65 + cg*4+1],
                  b2 = s_b[k*65 + cg*4+2], b3 = s_b[k*65 + cg*4+3];
      acc[0]=fmaf(a0,b0,acc[0]);  acc[1]=fmaf(a0,b1,acc[1]);
      acc[2]=fmaf(a0,b2,acc[2]);  acc[3]=fmaf(a0,b3,acc[3]);
      acc[4]=fmaf(a1,b0,acc[4]);  acc[5]=fmaf(a1,b1,acc[5]);
      acc[6]=fmaf(a1,b2,acc[6]);  acc[7]=fmaf(a1,b3,acc[7]);
      acc[8]=fmaf(a2,b0,acc[8]);  acc[9]=fmaf(a2,b1,acc[9]);
      acc[10]=fmaf(a2,b2,acc[10]); acc[11]=fmaf(a2,b3,acc[11]);
      acc[12]=fmaf(a3,b0,acc[12]); acc[13]=fmaf(a3,b1,acc[13]);
      acc[14]=fmaf(a3,b2,acc[14]); acc[15]=fmaf(a3,b3,acc[15]);
    }
  }
  #pragma unroll
  for (int i = 0; i < 4; ++i) {
    const int r = m0 + rg*4 + i;
    #pragma unroll
    for (int j = 0; j < 4; ++j) {
      const int n = n0 + cg*4 + j;
      outbuf[(long)r*256 + n] = fmaxf(acc[i*4+j] + bias[n], 0.f);
    }
  }
}

// ---------------- decoder GEMM 2 ----------------
__global__ __launch_bounds__(256) void dec2_kernel(
    const float* __restrict__ ain, const float* __restrict__ bt,
    const float* __restrict__ bias, float* __restrict__ outbuf)
{
  __shared__ float s_a[64*33];
  __shared__ float s_b[32*65];
  const int tid = threadIdx.x;
  const int m0 = blockIdx.x*64, n0 = blockIdx.y*64;
  float acc[16];
  #pragma unroll
  for (int q = 0; q < 16; ++q) acc[q] = 0.f;
  const int rg = tid >> 4, cg = tid & 15;
  for (int k0 = 0; k0 < 256; k0 += 32) {
    __syncthreads();
    {
      const int k = tid & 31, r8 = tid >> 5;
      #pragma unroll
      for (int p = 0; p < 8; ++p) {
        const int r = r8 + p*8;
        s_a[r*33 + k] = ain[(long)(m0+r)*256 + k0 + k];
      }
      const int n = tid & 63, kk = tid >> 6;
      #pragma unroll
      for (int p = 0; p < 8; ++p) {
        const int kr = kk + p*4;
        s_b[kr*65 + n] = bt[(k0+kr)*256 + n0 + n];
      }
    }
    __syncthreads();
    #pragma unroll 8
    for (int k = 0; k < 32; ++k) {
      const float a0 = s_a[(rg*4+0)*33 + k], a1 = s_a[(rg*4+1)*33 + k],
                  a2 = s_a[(rg*4+2)*33 + k], a3 = s_a[(rg*4+3)*33 + k];
      const float b0 = s_b[k*65 + cg*4+0], b1 = s_b[k*65 + cg*4+1],
                  b2 = s_b[k*65 + cg*4+2], b3 = s_b[k*65 + cg*4+3];
      acc[0]=fmaf(a0,b0,acc[0]);  acc[1]=fmaf(a0,b1,acc[1]);
      acc[2]=fmaf(a0,b2,acc[2]);  acc[3]=fmaf(a0,b3,acc[3]);
      acc[4]=fmaf(a1,b0,acc[4]);  acc[5]=fmaf(a1,b1,acc[5]);
      acc[6]=fmaf(a1,b2,acc[6]);  acc[7]=fmaf(a1,b3,acc[7]);
      acc[8]=fmaf(a2,b0,acc[8]);  acc[9]=fmaf(a2,b1,acc[9]);
      acc[10]=fmaf(a2,b2,acc[10]); acc[11]=fmaf(a2,b3,acc[11]);
      acc[12]=fmaf(a3,b0,acc[12]); acc[13]=fmaf(a3,b1,acc[13]);
      acc[14]=fmaf(a3,b2,acc[14]); acc[15]=fmaf(a3,b3,acc[15]);
    }
  }
  #pragma unroll
  for (int i = 0; i < 4; ++i) {
    const int r = m0 + rg*4 + i;
    #pragma unroll
    for (int j = 0; j < 4; ++j) {
      const int n = n0 + cg*4 + j;
      outbuf[(long)r*256 + n] = fmaxf(acc[i*4+j] + bias[n], 0.f);
    }
  }
}

// ---------------- decoder GEMM 3 + recon loss ----------------
__global__ __launch_bounds__(256) void dec3_kernel(
    const float* __restrict__ ain, const float* __restrict__ bt,
    const float* __restrict__ bias, const float* __restrict__ x,
    const float* __restrict__ tm, const float* __restrict__ imask,
    float* __restrict__ xhat, float* __restrict__ accums)
{
  __shared__ float s_a[64*33];
  __shared__ float s_b[32*65];
  const int tid = threadIdx.x;
  const int m0 = blockIdx.x*64, n0 = blockIdx.y*64;
  float acc[16];
  #pragma unroll
  for (int q = 0; q < 16; ++q) acc[q] = 0.f;
  const int rg = tid >> 4, cg = tid & 15;
  for (int k0 = 0; k0 < 256; k0 += 32) {
    __syncthreads();
    {
      const int k = tid & 31, r8 = tid >> 5;
      #pragma unroll
      for (int p = 0; p < 8; ++p) {
        const int r = r8 + p*8;
        s_a[r*33 + k] = ain[(long)(m0+r)*256 + k0 + k];
      }
      const int n = tid & 63, kk = tid >> 6;
      #pragma unroll
      for (int p = 0; p < 8; ++p) {
        const int kr = kk + p*4;
        const int col = n0 + n;
        s_b[kr*65 + n] = (col < 100) ? bt[(k0+kr)*100 + col] : 0.f;
      }
    }
    __syncthreads();
    #pragma unroll 8
    for (int k = 0; k < 32; ++k) {
      const float a0 = s_a[(rg*4+0)*33 + k], a1 = s_a[(rg*4+1)*33 + k],
                  a2 = s_a[(rg*4+2)*33 + k], a3 = s_a[(rg*4+3)*33 + k];
      const float b0 = s_b[k*65 + cg*4+0], b1 = s_b[k*65 + cg*4+1],
                  b2 = s_b[k*65 + cg*4+2], b3 = s_b[k*65 + cg*4+3];
      acc[0]=fmaf(a0,b0,acc[0]);  acc[1]=fmaf(a0,b1,acc[1]);
      acc[2]=fmaf(a0,b2,acc[2]);  acc[3]=fmaf(a0,b3,acc[3]);
      acc[4]=fmaf(a1,b0,acc[4]);  acc[5]=fmaf(a1,b1,acc[5]);
      acc[6]=fmaf(a1,b2,acc[6]);  acc[7]=fmaf(a1,b3,acc[7]);
      acc[8]=fmaf(a2,b0,acc[8]);  acc[9]=fmaf(a2,b1,acc[9]);
      acc[10]=fmaf(a2,b2,acc[10]); acc[11]=fmaf(a2,b3,acc[11]);
      acc[12]=fmaf(a3,b0,acc[12]); acc[13]=fmaf(a3,b1,acc[13]);
      acc[14]=fmaf(a3,b2,acc[14]); acc[15]=fmaf(a3,b3,acc[15]);
    }
  }
  float part = 0.f;
  #pragma unroll
  for (int i = 0; i < 4; ++i) {
    const int r = m0 + rg*4 + i;
    const float imv = imask[r];
    #pragma unroll
    for (int j = 0; j < 4; ++j) {
      const int col = n0 + cg*4 + j;
      if (col < 100) {
        const float xh = acc[i*4+j] + bias[col];
        xhat[(long)r*100 + col] = xh;
        const float wgt = imv * tm[(long)r*100 + col];
        const float df = xh - x[(long)r*100 + col];
        part = fmaf(df*df, wgt, part);
      }
    }
  }
  #pragma unroll
  for (int off = 32; off > 0; off >>= 1) part += __shfl_down(part, off);
  __shared__ float s_p[4];
  const int wid = tid >> 6, lane = tid & 63;
  if (lane == 0) s_p[wid] = part;
  __syncthreads();
  if (tid == 0) atomicAdd(&accums[0], s_p[0]+s_p[1]+s_p[2]+s_p[3]);
}

// ---------------- finalize scalars ----------------
__global__ void finalize_kernel(const float* __restrict__ accums, float* __restrict__ out) {
  if (threadIdx.x == 0 && blockIdx.x == 0) {
    out[5120000] = accums[0] / fmaxf(accums[2], 1.0f);
    out[5120001] = accums[1] / fmaxf(accums[3], 1.0f);
  }
}

extern "C" void kernel_launch(void* const* d_in, const int* in_sizes, int n_in,
                              void* d_out, int out_size, void* d_ws, size_t ws_size,
                              hipStream_t stream)
{
  (void)in_sizes; (void)n_in; (void)out_size; (void)ws_size;
  const float* x     = (const float*)d_in[0];
  const float* tmsk  = (const float*)d_in[1];
  const float* imask = (const float*)d_in[2];
  const float* w1    = (const float*)d_in[3];
  const float* b1    = (const float*)d_in[4];
  const float* w2    = (const float*)d_in[5];
  const float* b2    = (const float*)d_in[6];
  const float* latw  = (const float*)d_in[7];
  const float* latb  = (const float*)d_in[8];
  const float* cb    = (const float*)d_in[9];
  const float* d1w   = (const float*)d_in[10];
  const float* d1b   = (const float*)d_in[11];
  const float* d2w   = (const float*)d_in[12];
  const float* d2b   = (const float*)d_in[13];
  const float* d3w   = (const float*)d_in[14];
  const float* d3b   = (const float*)d_in[15];
  float* out = (float*)d_out;
  float* ws  = (float*)d_ws;

  float* zbuf    = ws + WS_ZBUF;
  float* rown    = ws + WS_ROWNORM;
  ushort_t* bhi  = (ushort_t*)(ws + WS_BFRAG);
  ushort_t* blo  = bhi + 12288;
  float* latwt   = ws + WS_LATWT;
  float* d1t     = ws + WS_D1T;
  float* d2t     = ws + WS_D2T;
  float* d3t     = ws + WS_D3T;
  float* cbnorm  = ws + WS_CBNORM;
  float* accums  = ws + WS_ACCUMS;
  u64*   gbest   = (u64*)(ws + WS_GBEST);
  float* h1      = ws + WS_H1;
  float* h2      = ws + WS_H2;
  float* xhat    = out;
  float* out_idx = out + 5120002;

  hipMemsetAsync(gbest, 0xFF, 51200*sizeof(u64), stream);
  hipMemsetAsync(accums, 0, 8*sizeof(float), stream);

  prep_kernel<<<512, 256, 0, stream>>>(w2, latw, d1w, d2w, d3w, cb,
                                       bhi, blo, latwt, d1t, d2t, d3t, cbnorm);
  masksum_kernel<<<1024, 256, 0, stream>>>(imask, tmsk, accums);
  encoder_kernel<<<51200, 256, 0, stream>>>(x, tmsk, imask, w1, b1, bhi, blo, b2,
                                            latwt, latb, zbuf, rown);
  vq_kernel<<<dim3(800, 8), 256, 0, stream>>>(zbuf, cb, rown, cbnorm, gbest);
  vqloss_kernel<<<256, 256, 0, stream>>>(zbuf, cb, imask, gbest, out_idx, accums);
  dec1_kernel<<<dim3(800, 4), 256, 0, stream>>>(cb, gbest, imask, d1t, d1b, h1);
  dec2_kernel<<<dim3(800, 4), 256, 0, stream>>>(h1, d2t, d2b, h2);
  dec3_kernel<<<dim3(800, 2), 256, 0, stream>>>(h2, d3t, d3b, x, tmsk, imask, xhat, accums);
  finalize_kernel<<<1, 64, 0, stream>>>(accums, out);
}

// Round 4
// 793.566 us; speedup vs baseline: 2.3940x; 1.2679x over previous
//
#include <hip/hip_runtime.h>
#include <stdint.h>

typedef unsigned long long u64;
typedef unsigned short ushort_t;
typedef __attribute__((ext_vector_type(8))) short short8;
typedef __attribute__((ext_vector_type(8))) _Float16 half8;
typedef __attribute__((ext_vector_type(16))) float f32x16;

// Dims: B=512,N=100 -> M=51200; T=100, L=50 conv pos, HE=64, E=128, NE=512, HD=256.

// ---------------- workspace layout (float offsets) ----------------
// NOTE R3 bug: zhi/zlo are 51200*128 ushorts = 3,276,800 floats EACH.
#define WS_ROWNORM  0ll          // 51200 f32                      -> end    51,200
#define WS_ZHI      51200ll      // 3,276,800 f (f16 hi bits)      -> end 3,328,000
#define WS_ZLO      3328000ll    // 3,276,800 f (f16 lo bits)      -> end 6,604,800
#define WS_ENCBHI   6604800ll    // 12288 ushort = 6144 f          -> end 6,610,944
#define WS_ENCBLO   6610944ll    // 6144 f                         -> end 6,617,088
#define WS_CBHI     6617088ll    // 65536 ushort = 32768 f         -> end 6,649,856
#define WS_CBLO     6649856ll    // 32768 f                        -> end 6,682,624
#define WS_CBNORM   6682624ll    // 512 f                          -> end 6,683,136
#define WS_D1F      6683136ll    // 32768 ushort = 16384 f         -> end 6,699,520
#define WS_D2F      6699520ll    // 65536 ushort = 32768 f         -> end 6,732,288
#define WS_D3F      6732288ll    // 32768 ushort = 16384 f         -> end 6,748,672
#define WS_ACCUMS   6748672ll    // 8 f32                          -> end 6,748,680
#define WS_GBEST    6748680ll    // 51200 u64 = 102,400 f (byte%8==0) -> end 6,851,080
#define WS_H1       6851080ll    // 51200*256 ushort = 6,553,600 f -> end 13,404,680
#define WS_H2       13404680ll   // 6,553,600 f                    -> end 19,958,280 (~79.8 MB)

__device__ __host__ inline ushort_t bf16_rn(float v) {
  unsigned u = __float_as_uint(v);
  unsigned r = (u + 0x7fffu + ((u >> 16) & 1u)) >> 16;
  return (ushort_t)r;
}
union h2u { _Float16 h; unsigned short u; };
union s2h { short8 s; half8 h; };

__device__ inline int rowfn(int r, int half) { return (r & 3) + 8*(r >> 2) + 4*half; }

// ---------------- prep: frag-pack all weights + codebook norms ----------------
__global__ __launch_bounds__(256) void prep_kernel(
    const float* __restrict__ w2, const float* __restrict__ cb,
    const float* __restrict__ d1w, const float* __restrict__ d2w,
    const float* __restrict__ d3w,
    ushort_t* __restrict__ ebhi, ushort_t* __restrict__ eblo,
    ushort_t* __restrict__ cbhi, ushort_t* __restrict__ cblo,
    ushort_t* __restrict__ d1f, ushort_t* __restrict__ d2f,
    ushort_t* __restrict__ d3f, float* __restrict__ cbnorm)
{
  const int total = 12288 + 65536 + 32768 + 65536 + 32768 + 512;
  for (int i = blockIdx.x*256 + threadIdx.x; i < total; i += gridDim.x*256) {
    int idx = i;
    if (idx < 12288) {
      // encoder conv2 B-frags (bf16 hi/lo), 32x32x16: f=((t*2+nt)*4+kt)
      int j = idx & 7, l6 = (idx >> 3) & 63, f = idx >> 9;
      int kt = f & 3, ntt = (f >> 2) & 1, t = f >> 3;
      int oc = ntt*32 + (l6 & 31);
      int ic = kt*16 + (l6 >> 5)*8 + j;
      float v = w2[(oc*64 + ic)*3 + t];
      ushort_t hi = bf16_rn(v);
      float hf = __uint_as_float(((unsigned)hi) << 16);
      ebhi[idx] = hi; eblo[idx] = bf16_rn(v - hf); continue;
    }
    idx -= 12288;
    if (idx < 65536) {
      // codebook f16 hi/lo frags, scaled x512: ntg16 x kt8
      int j = idx & 7, l6 = (idx >> 3) & 63, f = idx >> 9;
      int kt = f & 7, ntg = f >> 3;
      int k = kt*16 + (l6 >> 5)*8 + j;
      int n = ntg*32 + (l6 & 31);
      float v = cb[n*128 + k] * 512.0f;
      h2u a, b; a.h = (_Float16)v;
      b.h = (_Float16)(v - (float)a.h);
      cbhi[idx] = a.u; cblo[idx] = b.u; continue;
    }
    idx -= 65536;
    if (idx < 32768) {
      // d1 bf16 frags: ntg8 x kt8, B[k][n]=d1w[n][k]
      int j = idx & 7, l6 = (idx >> 3) & 63, f = idx >> 9;
      int kt = f & 7, ntg = f >> 3;
      int k = kt*16 + (l6 >> 5)*8 + j;
      int n = ntg*32 + (l6 & 31);
      d1f[idx] = bf16_rn(d1w[n*128 + k]); continue;
    }
    idx -= 32768;
    if (idx < 65536) {
      // d2 bf16 frags: ntg8 x kt16
      int j = idx & 7, l6 = (idx >> 3) & 63, f = idx >> 9;
      int kt = f & 15, ntg = f >> 4;
      int k = kt*16 + (l6 >> 5)*8 + j;
      int n = ntg*32 + (l6 & 31);
      d2f[idx] = bf16_rn(d2w[n*256 + k]); continue;
    }
    idx -= 65536;
    if (idx < 32768) {
      // d3 bf16 frags: ntg4 x kt16, cols>=100 zero
      int j = idx & 7, l6 = (idx >> 3) & 63, f = idx >> 9;
      int kt = f & 15, ntg = f >> 4;
      int k = kt*16 + (l6 >> 5)*8 + j;
      int n = ntg*32 + (l6 & 31);
      d3f[idx] = (n < 100) ? bf16_rn(d3w[n*256 + k]) : (ushort_t)0; continue;
    }
    idx -= 32768;
    { double s = 0.0; const float* c = cb + idx*128;
      for (int e = 0; e < 128; ++e) { double v = (double)c[e]; s += v*v; }
      cbnorm[idx] = (float)s; }
  }
}

// ---------------- mask sums ----------------
__global__ __launch_bounds__(256) void masksum_kernel(
    const float* __restrict__ imask, const float* __restrict__ tm,
    float* __restrict__ accums)
{
  float rw = 0.f, si = 0.f;
  const int total = 51200*100;
  for (int i = blockIdx.x*256 + threadIdx.x; i < total; i += gridDim.x*256) {
    int m = i / 100;
    rw += imask[m] * tm[i];
    if (i < 51200) si += imask[i];
  }
  #pragma unroll
  for (int off = 32; off > 0; off >>= 1) { rw += __shfl_down(rw, off); si += __shfl_down(si, off); }
  __shared__ float s_rw[4], s_si[4];
  int wid = threadIdx.x >> 6, lane = threadIdx.x & 63;
  if (lane == 0) { s_rw[wid] = rw; s_si[wid] = si; }
  __syncthreads();
  if (threadIdx.x == 0) {
    atomicAdd(&accums[2], s_rw[0]+s_rw[1]+s_rw[2]+s_rw[3]);
    atomicAdd(&accums[3], s_si[0]+s_si[1]+s_si[2]+s_si[3]);
  }
}

// ---------------- encoder: persistent blocks ----------------
// w1,b1,b2,latw,latb intentionally NOT __restrict: keeps their loads in-loop
// (L1-hot) instead of hoisted into ~112 registers.
__global__ __launch_bounds__(256) void encoder_kernel(
    const float* __restrict__ x, const float* __restrict__ tm,
    const float* __restrict__ imask,
    const float* w1, const float* b1,
    const ushort_t* __restrict__ ebhi, const ushort_t* __restrict__ eblo,
    const float* b2, const float* latw, const float* latb,
    ushort_t* zhi, ushort_t* zlo, float* rownorm)
{
  __shared__ float s_h0[104];
  __shared__ ushort_t s_Hhi[52*72];
  __shared__ ushort_t s_Hlo[52*72];
  __shared__ float s_red[2][64];
  __shared__ float s_hm[64];
  __shared__ float s_z[128];
  const int tid = threadIdx.x;
  const int wv   = __builtin_amdgcn_readfirstlane((int)(tid >> 6));
  const int lane = tid & 63;
  const int ln31 = lane & 31, half = lane >> 5;
  const int mt = wv >> 1, nt = wv & 1;
  const int o0 = wv*16;

  // one-time LDS halo init
  if (tid < 104) s_h0[tid] = 0.f;
  if (tid < 72) { s_Hhi[tid] = 0; s_Hlo[tid] = 0; s_Hhi[51*72+tid] = 0; s_Hlo[51*72+tid] = 0; }

  // hoisted per-wave constants
  short8 Bh[12], Bl[12];
  {
    const short8* bh8 = (const short8*)ebhi;
    const short8* bl8 = (const short8*)eblo;
    #pragma unroll
    for (int t = 0; t < 3; ++t)
      #pragma unroll
      for (int kt = 0; kt < 4; ++kt) {
        const int f = ((t*2 + nt)*4 + kt);
        Bh[t*4+kt] = bh8[f*64 + lane];
        Bl[t*4+kt] = bl8[f*64 + lane];
      }
  }
  const float bias2 = b2[nt*32 + ln31];
  const float latbv = (tid < 128) ? latb[tid] : 0.f;
  __syncthreads();

  for (int m = blockIdx.x; m < 51200; m += gridDim.x) {
    const float imv = imask[m];   // uniform -> scalar load
    if (tid < 50) {
      const float2 xv = *(const float2*)(x  + (long)m*100 + tid*2);
      const float2 tv = *(const float2*)(tm + (long)m*100 + tid*2);
      s_h0[1 + tid]      = xv.x * tv.x * imv;   // channel 0, pos tid
      s_h0[52 + 1 + tid] = xv.y * tv.y * imv;   // channel 1
    }
    __syncthreads();   // SYNC_B

    // conv1 (f32) + bf16 hi/lo split, packed b128 LDS writes
    {
      const int ll = (lane < 50) ? lane : 0;
      const float a0 = s_h0[ll],    a1 = s_h0[ll+1],    a2 = s_h0[ll+2];
      const float c0 = s_h0[52+ll], c1 = s_h0[52+ll+1], c2 = s_h0[52+ll+2];
      ushort_t hi16[16], lo16[16];
      #pragma unroll
      for (int oo = 0; oo < 16; ++oo) {
        const int o = o0 + oo;
        const float* w = w1 + o*6;
        float h = b1[o];
        h = fmaf(w[0], a0, h); h = fmaf(w[1], a1, h); h = fmaf(w[2], a2, h);
        h = fmaf(w[3], c0, h); h = fmaf(w[4], c1, h); h = fmaf(w[5], c2, h);
        h = fmaxf(h, 0.f);
        if (lane >= 50) h = 0.f;
        const ushort_t hh = bf16_rn(h);
        const float hf = __uint_as_float(((unsigned)hh) << 16);
        hi16[oo] = hh; lo16[oo] = bf16_rn(h - hf);
      }
      if (lane < 51) {
        short8* dh = (short8*)(s_Hhi + (lane+1)*72 + o0);
        short8* dl = (short8*)(s_Hlo + (lane+1)*72 + o0);
        dh[0] = *(short8*)&hi16[0]; dh[1] = *(short8*)&hi16[8];
        dl[0] = *(short8*)&lo16[0]; dl[1] = *(short8*)&lo16[8];
      }
    }
    __syncthreads();   // SYNC_C

    // conv2 MFMA: 3 taps x 4 k-tiles x 3 passes
    f32x16 acc;
    #pragma unroll
    for (int q = 0; q < 16; ++q) acc[q] = 0.f;
    #pragma unroll
    for (int t = 0; t < 3; ++t) {
      int rowA = mt*32 + ln31 + t;
      if (rowA > 51) rowA = 51;
      const int base8 = rowA*9 + half;   // short8 index (72/8=9)
      #pragma unroll
      for (int kt = 0; kt < 4; ++kt) {
        const short8 ah = ((const short8*)s_Hhi)[base8 + kt*2];
        const short8 al = ((const short8*)s_Hlo)[base8 + kt*2];
        acc = __builtin_amdgcn_mfma_f32_32x32x16_bf16(ah, Bh[t*4+kt], acc, 0, 0, 0);
        acc = __builtin_amdgcn_mfma_f32_32x32x16_bf16(ah, Bl[t*4+kt], acc, 0, 0, 0);
        acc = __builtin_amdgcn_mfma_f32_32x32x16_bf16(al, Bh[t*4+kt], acc, 0, 0, 0);
      }
    }
    // relu + mean over pos<50
    {
      float sum = 0.f;
      #pragma unroll
      for (int r = 0; r < 16; ++r) {
        const int mpos = mt*32 + rowfn(r, half);
        const float v = fmaxf(acc[r] + bias2, 0.f);
        if (mpos < 50) sum += v;
      }
      sum += __shfl_xor(sum, 32);
      if (half == 0) s_red[mt][nt*32 + ln31] = sum;
    }
    __syncthreads();   // SYNC_D
    if (tid < 64) s_hm[tid] = (s_red[0][tid] + s_red[1][tid]) * 0.02f;
    __syncthreads();   // SYNC_E

    // latent (f32), contiguous latw[e][ic]
    if (tid < 128) {
      float a = latbv;
      const float4* wp = (const float4*)(latw + tid*64);
      const float4* hp = (const float4*)s_hm;
      #pragma unroll
      for (int q = 0; q < 16; ++q) {
        const float4 w4 = wp[q]; const float4 h4 = hp[q];
        a = fmaf(w4.x, h4.x, a); a = fmaf(w4.y, h4.y, a);
        a = fmaf(w4.z, h4.z, a); a = fmaf(w4.w, h4.w, a);
      }
      a *= imv;
      s_z[tid] = a;
      h2u zh; zh.h = (_Float16)a;
      h2u zl; zl.h = (_Float16)(a - (float)zh.h);
      zhi[(long)m*128 + tid] = zh.u;
      zlo[(long)m*128 + tid] = zl.u;
    }
    __syncthreads();   // SYNC_F
    if (tid < 64) {
      float v = s_z[tid]*s_z[tid] + s_z[tid+64]*s_z[tid+64];
      #pragma unroll
      for (int off = 32; off > 0; off >>= 1) v += __shfl_down(v, off);
      if (tid == 0) rownorm[m] = v;
    }
  }
}

// ---------------- VQ: f16 3-pass MFMA, 32 rows x all 512 codes per block ----------------
__global__ __launch_bounds__(256) void vq_kernel(
    const ushort_t* __restrict__ zhi, const ushort_t* __restrict__ zlo,
    const ushort_t* __restrict__ cbhi, const ushort_t* __restrict__ cblo,
    const float* __restrict__ rownorm, const float* __restrict__ cbnorm,
    u64* __restrict__ gbest)
{
  __shared__ ushort_t s_ah[32*136];
  __shared__ ushort_t s_al[32*136];
  __shared__ float s_rn[32];
  __shared__ u64 s_best[32];
  const int tid = threadIdx.x;
  const int m0 = blockIdx.x * 32;
  {
    const short8* gh = (const short8*)(zhi + (long)m0*128);
    const short8* gl = (const short8*)(zlo + (long)m0*128);
    const int row = tid >> 3, c8 = (tid & 7)*2;   // 16 shorts per thread
    ((short8*)s_ah)[row*17 + c8]     = gh[tid*2];
    ((short8*)s_ah)[row*17 + c8 + 1] = gh[tid*2 + 1];
    ((short8*)s_al)[row*17 + c8]     = gl[tid*2];
    ((short8*)s_al)[row*17 + c8 + 1] = gl[tid*2 + 1];
  }
  if (tid < 32) { s_rn[tid] = rownorm[m0 + tid]; s_best[tid] = ~0ULL; }
  __syncthreads();

  const int wv = tid >> 6, lane = tid & 63;
  const int ln31 = lane & 31, half = lane >> 5;
  float rnv[16];
  #pragma unroll
  for (int r = 0; r < 16; ++r) rnv[r] = s_rn[rowfn(r, half)];

  u64 best[16];
  #pragma unroll
  for (int r = 0; r < 16; ++r) best[r] = ~0ULL;

  const short8* ch8 = (const short8*)cbhi;
  const short8* cl8 = (const short8*)cblo;
  for (int ct = 0; ct < 4; ++ct) {
    const int ntg = wv*4 + ct;
    half8 Bh[8], Bl[8];
    #pragma unroll
    for (int kt = 0; kt < 8; ++kt) {
      s2h a, b;
      a.s = ch8[(ntg*8 + kt)*64 + lane];
      b.s = cl8[(ntg*8 + kt)*64 + lane];
      Bh[kt] = a.h; Bl[kt] = b.h;
    }
    f32x16 acc;
    #pragma unroll
    for (int q = 0; q < 16; ++q) acc[q] = 0.f;
    const int base8 = ln31*17 + half;
    #pragma unroll
    for (int kt = 0; kt < 8; ++kt) {
      s2h ah, al;
      ah.s = ((const short8*)s_ah)[base8 + kt*2];
      al.s = ((const short8*)s_al)[base8 + kt*2];
      acc = __builtin_amdgcn_mfma_f32_32x32x16_f16(ah.h, Bh[kt], acc, 0, 0, 0);
      acc = __builtin_amdgcn_mfma_f32_32x32x16_f16(ah.h, Bl[kt], acc, 0, 0, 0);
      acc = __builtin_amdgcn_mfma_f32_32x32x16_f16(al.h, Bh[kt], acc, 0, 0, 0);
    }
    const int code = ntg*32 + ln31;
    const float nrm = cbnorm[code];
    #pragma unroll
    for (int r = 0; r < 16; ++r) {
      // p' = z.(512c); d = fl(A - p'/256) + n  == np's round(A-2p)+n structure
      const float t = fmaf(-0.00390625f, acc[r], rnv[r]);
      const float d = t + nrm;
      const u64 pk = ((u64)__float_as_uint(d) << 32) | (u64)(unsigned)code;
      if (pk < best[r]) best[r] = pk;
    }
  }
  #pragma unroll
  for (int r = 0; r < 16; ++r) atomicMin(&s_best[rowfn(r, half)], best[r]);
  __syncthreads();
  if (tid < 32) gbest[m0 + tid] = s_best[tid];
}

// ---------------- indices + vq loss from packed distances ----------------
__global__ __launch_bounds__(256) void vqloss_kernel(
    const float* __restrict__ imask, const u64* __restrict__ gbest,
    float* __restrict__ out_idx, float* __restrict__ accums)
{
  const int r = blockIdx.x*256 + threadIdx.x;
  float vqp = 0.f;
  if (r < 51200) {
    const u64 pk = gbest[r];
    const int idx = (int)(unsigned)(pk & 0xffffffffULL);
    const float d = __uint_as_float((unsigned)(pk >> 32));
    const float imv = imask[r];
    out_idx[r] = (imv > 0.f) ? (float)idx : -1.0f;
    vqp = 1.25f * d * (1.0f/128.0f) * imv;
  }
  #pragma unroll
  for (int off = 32; off > 0; off >>= 1) vqp += __shfl_down(vqp, off);
  __shared__ float s_p[4];
  const int wid = threadIdx.x >> 6, lane = threadIdx.x & 63;
  if (lane == 0) s_p[wid] = vqp;
  __syncthreads();
  if (threadIdx.x == 0) atomicAdd(&accums[1], s_p[0]+s_p[1]+s_p[2]+s_p[3]);
}

// ---------------- decoder GEMM 1: h1 = relu(zq @ d1^T + b), bf16 MFMA ----------------
__global__ __launch_bounds__(256) void dec1_kernel(
    const float* __restrict__ cb, const u64* __restrict__ gbest,
    const float* __restrict__ imask, const ushort_t* __restrict__ bfrag,
    const float* __restrict__ bias, ushort_t* __restrict__ h1out)
{
  __shared__ ushort_t s_a[64*136];
  __shared__ int s_idx[64];
  __shared__ float s_act[64];
  const int tid = threadIdx.x;
  const long m0 = (long)blockIdx.x * 64;
  if (tid < 64) {
    s_idx[tid] = (int)(unsigned)(gbest[m0 + tid] & 0xffffffffULL);
    s_act[tid] = imask[m0 + tid];
  }
  __syncthreads();
  {
    const int row = tid >> 2, seg = tid & 3;
    const float4* src = (const float4*)(cb + (long)s_idx[row]*128 + seg*32);
    const float im = s_act[row];
    ushort_t tmp[32];
    #pragma unroll
    for (int q = 0; q < 8; ++q) {
      const float4 v = src[q];
      tmp[q*4+0] = bf16_rn(v.x*im); tmp[q*4+1] = bf16_rn(v.y*im);
      tmp[q*4+2] = bf16_rn(v.z*im); tmp[q*4+3] = bf16_rn(v.w*im);
    }
    short8* dst = (short8*)(s_a + row*136 + seg*32);
    #pragma unroll
    for (int q = 0; q < 4; ++q) dst[q] = *(short8*)&tmp[q*8];
  }
  __syncthreads();
  const int wv = tid >> 6, lane = tid & 63;
  const int ln31 = lane & 31, half = lane >> 5;
  const short8* bf = (const short8*)bfrag;
  #pragma unroll
  for (int nti = 0; nti < 2; ++nti) {
    const int ntg = wv + nti*4;
    short8 B[8];
    #pragma unroll
    for (int kt = 0; kt < 8; ++kt) B[kt] = bf[(ntg*8 + kt)*64 + lane];
    const float bv = bias[ntg*32 + ln31];
    #pragma unroll
    for (int mtl = 0; mtl < 2; ++mtl) {
      f32x16 acc;
      #pragma unroll
      for (int q = 0; q < 16; ++q) acc[q] = 0.f;
      const int base8 = (mtl*32 + ln31)*17 + half;
      #pragma unroll
      for (int kt = 0; kt < 8; ++kt) {
        const short8 a = ((const short8*)s_a)[base8 + kt*2];
        acc = __builtin_amdgcn_mfma_f32_32x32x16_bf16(a, B[kt], acc, 0, 0, 0);
      }
      const int col = ntg*32 + ln31;
      #pragma unroll
      for (int r = 0; r < 16; ++r) {
        const long row = m0 + mtl*32 + rowfn(r, half);
        h1out[row*256 + col] = bf16_rn(fmaxf(acc[r] + bv, 0.f));
      }
    }
  }
}

// ---------------- decoder GEMM 2: h2 = relu(h1 @ d2^T + b), K=256 ----------------
__global__ __launch_bounds__(256) void dec2_kernel(
    const ushort_t* __restrict__ ain, const ushort_t* __restrict__ bfrag,
    const float* __restrict__ bias, ushort_t* __restrict__ outbuf)
{
  __shared__ ushort_t s_a[64*264];
  const int tid = threadIdx.x;
  const long m0 = (long)blockIdx.x * 64;
  {
    const int row = tid >> 2, seg = tid & 3;
    const short8* src = (const short8*)(ain + (m0 + row)*256 + seg*64);
    short8* dst = (short8*)(s_a + row*264 + seg*64);
    #pragma unroll
    for (int q = 0; q < 8; ++q) dst[q] = src[q];
  }
  __syncthreads();
  const int wv = tid >> 6, lane = tid & 63;
  const int ln31 = lane & 31, half = lane >> 5;
  const short8* bf = (const short8*)bfrag;
  #pragma unroll
  for (int nti = 0; nti < 2; ++nti) {
    const int ntg = wv + nti*4;
    short8 B[16];
    #pragma unroll
    for (int kt = 0; kt < 16; ++kt) B[kt] = bf[(ntg*16 + kt)*64 + lane];
    const float bv = bias[ntg*32 + ln31];
    #pragma unroll
    for (int mtl = 0; mtl < 2; ++mtl) {
      f32x16 acc;
      #pragma unroll
      for (int q = 0; q < 16; ++q) acc[q] = 0.f;
      const int base8 = (mtl*32 + ln31)*33 + half;
      #pragma unroll
      for (int kt = 0; kt < 16; ++kt) {
        const short8 a = ((const short8*)s_a)[base8 + kt*2];
        acc = __builtin_amdgcn_mfma_f32_32x32x16_bf16(a, B[kt], acc, 0, 0, 0);
      }
      const int col = ntg*32 + ln31;
      #pragma unroll
      for (int r = 0; r < 16; ++r) {
        const long row = m0 + mtl*32 + rowfn(r, half);
        outbuf[row*256 + col] = bf16_rn(fmaxf(acc[r] + bv, 0.f));
      }
    }
  }
}

// ---------------- decoder GEMM 3: x_hat = h2 @ d3^T + b (N=100) + recon loss ----------------
__global__ __launch_bounds__(256) void dec3_kernel(
    const ushort_t* __restrict__ ain, const ushort_t* __restrict__ bfrag,
    const float* __restrict__ bias, const float* __restrict__ x,
    const float* __restrict__ tm, const float* __restrict__ imask,
    float* __restrict__ xhat, float* __restrict__ accums)
{
  __shared__ ushort_t s_a[64*264];
  const int tid = threadIdx.x;
  const long m0 = (long)blockIdx.x * 64;
  {
    const int row = tid >> 2, seg = tid & 3;
    const short8* src = (const short8*)(ain + (m0 + row)*256 + seg*64);
    short8* dst = (short8*)(s_a + row*264 + seg*64);
    #pragma unroll
    for (int q = 0; q < 8; ++q) dst[q] = src[q];
  }
  __syncthreads();
  const int wv = tid >> 6, lane = tid & 63;
  const int ln31 = lane & 31, half = lane >> 5;
  const short8* bf = (const short8*)bfrag;
  const int ntg = wv;
  short8 B[16];
  #pragma unroll
  for (int kt = 0; kt < 16; ++kt) B[kt] = bf[(ntg*16 + kt)*64 + lane];
  const int col = ntg*32 + ln31;
  const float bv = (col < 100) ? bias[col] : 0.f;
  float part = 0.f;
  #pragma unroll
  for (int mtl = 0; mtl < 2; ++mtl) {
    f32x16 acc;
    #pragma unroll
    for (int q = 0; q < 16; ++q) acc[q] = 0.f;
    const int base8 = (mtl*32 + ln31)*33 + half;
    #pragma unroll
    for (int kt = 0; kt < 16; ++kt) {
      const short8 a = ((const short8*)s_a)[base8 + kt*2];
      acc = __builtin_amdgcn_mfma_f32_32x32x16_bf16(a, B[kt], acc, 0, 0, 0);
    }
    if (col < 100) {
      #pragma unroll
      for (int r = 0; r < 16; ++r) {
        const long row = m0 + mtl*32 + rowfn(r, half);
        const float xh = acc[r] + bv;
        xhat[row*100 + col] = xh;
        const float wgt = imask[row] * tm[row*100 + col];
        const float df = xh - x[row*100 + col];
        part = fmaf(df*df, wgt, part);
      }
    }
  }
  #pragma unroll
  for (int off = 32; off > 0; off >>= 1) part += __shfl_down(part, off);
  __shared__ float s_p[4];
  if (lane == 0) s_p[wv] = part;
  __syncthreads();
  if (tid == 0) atomicAdd(&accums[0], s_p[0]+s_p[1]+s_p[2]+s_p[3]);
}

// ---------------- finalize scalars ----------------
__global__ void finalize_kernel(const float* __restrict__ accums, float* __restrict__ out) {
  if (threadIdx.x == 0 && blockIdx.x == 0) {
    out[5120000] = accums[0] / fmaxf(accums[2], 1.0f);
    out[5120001] = accums[1] / fmaxf(accums[3], 1.0f);
  }
}

extern "C" void kernel_launch(void* const* d_in, const int* in_sizes, int n_in,
                              void* d_out, int out_size, void* d_ws, size_t ws_size,
                              hipStream_t stream)
{
  (void)in_sizes; (void)n_in; (void)out_size; (void)ws_size;
  const float* x     = (const float*)d_in[0];
  const float* tmsk  = (const float*)d_in[1];
  const float* imask = (const float*)d_in[2];
  const float* w1    = (const float*)d_in[3];
  const float* b1    = (const float*)d_in[4];
  const float* w2    = (const float*)d_in[5];
  const float* b2    = (const float*)d_in[6];
  const float* latw  = (const float*)d_in[7];
  const float* latb  = (const float*)d_in[8];
  const float* cb    = (const float*)d_in[9];
  const float* d1w   = (const float*)d_in[10];
  const float* d1b   = (const float*)d_in[11];
  const float* d2w   = (const float*)d_in[12];
  const float* d2b   = (const float*)d_in[13];
  const float* d3w   = (const float*)d_in[14];
  const float* d3b   = (const float*)d_in[15];
  float* out = (float*)d_out;
  float* ws  = (float*)d_ws;

  float*    rown   = ws + WS_ROWNORM;
  ushort_t* zhi    = (ushort_t*)(ws + WS_ZHI);
  ushort_t* zlo    = (ushort_t*)(ws + WS_ZLO);
  ushort_t* ebhi   = (ushort_t*)(ws + WS_ENCBHI);
  ushort_t* eblo   = (ushort_t*)(ws + WS_ENCBLO);
  ushort_t* cbhi   = (ushort_t*)(ws + WS_CBHI);
  ushort_t* cblo   = (ushort_t*)(ws + WS_CBLO);
  float*    cbnorm = ws + WS_CBNORM;
  ushort_t* d1f    = (ushort_t*)(ws + WS_D1F);
  ushort_t* d2f    = (ushort_t*)(ws + WS_D2F);
  ushort_t* d3f    = (ushort_t*)(ws + WS_D3F);
  float*    accums = ws + WS_ACCUMS;
  u64*      gbest  = (u64*)(ws + WS_GBEST);
  ushort_t* h1     = (ushort_t*)(ws + WS_H1);
  ushort_t* h2     = (ushort_t*)(ws + WS_H2);
  float* xhat    = out;
  float* out_idx = out + 5120002;

  hipMemsetAsync(accums, 0, 8*sizeof(float), stream);

  prep_kernel<<<512, 256, 0, stream>>>(w2, cb, d1w, d2w, d3w,
                                       ebhi, eblo, cbhi, cblo, d1f, d2f, d3f, cbnorm);
  masksum_kernel<<<1024, 256, 0, stream>>>(imask, tmsk, accums);
  encoder_kernel<<<2048, 256, 0, stream>>>(x, tmsk, imask, w1, b1, ebhi, eblo, b2,
                                           latw, latb, zhi, zlo, rown);
  vq_kernel<<<1600, 256, 0, stream>>>(zhi, zlo, cbhi, cblo, rown, cbnorm, gbest);
  vqloss_kernel<<<200, 256, 0, stream>>>(imask, gbest, out_idx, accums);
  dec1_kernel<<<800, 256, 0, stream>>>(cb, gbest, imask, d1f, d1b, h1);
  dec2_kernel<<<800, 256, 0, stream>>>(h1, d2f, d2b, h2);
  dec3_kernel<<<800, 256, 0, stream>>>(h2, d3f, d3b, x, tmsk, imask, xhat, accums);
  finalize_kernel<<<1, 64, 0, stream>>>(accums, out);
}

// Round 5
// 734.741 us; speedup vs baseline: 2.5857x; 1.0801x over previous
//
#include <hip/hip_runtime.h>
#include <stdint.h>

typedef unsigned long long u64;
typedef unsigned short ushort_t;
typedef __attribute__((ext_vector_type(8))) short short8;
typedef __attribute__((ext_vector_type(8))) _Float16 half8;
typedef __attribute__((ext_vector_type(16))) float f32x16;

// Dims: B=512,N=100 -> M=51200; T=100, L=50 conv pos, HE=64, E=128, NE=512, HD=256.

// ---------------- workspace layout (float offsets) ----------------
#define WS_RNP0     0ll          // 51200 f32 (rownorm partial wave0)  -> end    51,200
#define WS_RNP1     51200ll      // 51200 f32 (partial wave1)          -> end   102,400
#define WS_ZHI      102400ll     // 51200*128 ushort = 3,276,800 f     -> end 3,379,200
#define WS_ZLO      3379200ll    // 3,276,800 f                        -> end 6,656,000
#define WS_ENCBHI   6656000ll    // 12288 ushort = 6144 f              -> end 6,662,144
#define WS_ENCBLO   6662144ll    // 6144 f                             -> end 6,668,288
#define WS_CBHI     6668288ll    // 65536 ushort = 32768 f             -> end 6,701,056
#define WS_CBLO     6701056ll    // 32768 f                            -> end 6,733,824
#define WS_CBNORM   6733824ll    // 512 f                              -> end 6,734,336
#define WS_D1F      6734336ll    // 32768 ushort = 16384 f             -> end 6,750,720
#define WS_D2F      6750720ll    // 65536 ushort = 32768 f             -> end 6,783,488
#define WS_D3F      6783488ll    // 32768 ushort = 16384 f             -> end 6,799,872
#define WS_ACCUMS   6799872ll    // 8 f32                              -> end 6,799,880
#define WS_GBEST    6799880ll    // 51200 u64 = 102,400 f (byte%8==0)  -> end 6,902,280
#define WS_H1       6902280ll    // 51200*256 ushort = 6,553,600 f     -> end 13,455,880
#define WS_H2       13455880ll   // 6,553,600 f                        -> end 20,009,480 (~80 MB)

__device__ __host__ inline ushort_t bf16_rn(float v) {
  unsigned u = __float_as_uint(v);
  unsigned r = (u + 0x7fffu + ((u >> 16) & 1u)) >> 16;
  return (ushort_t)r;
}
union h2u { _Float16 h; unsigned short u; };
union s2h { short8 s; half8 h; };

__device__ inline int rowfn(int r, int half) { return (r & 3) + 8*(r >> 2) + 4*half; }

// ---------------- prep: frag-pack all weights + codebook norms ----------------
__global__ __launch_bounds__(256) void prep_kernel(
    const float* __restrict__ w2, const float* __restrict__ cb,
    const float* __restrict__ d1w, const float* __restrict__ d2w,
    const float* __restrict__ d3w,
    ushort_t* __restrict__ ebhi, ushort_t* __restrict__ eblo,
    ushort_t* __restrict__ cbhi, ushort_t* __restrict__ cblo,
    ushort_t* __restrict__ d1f, ushort_t* __restrict__ d2f,
    ushort_t* __restrict__ d3f, float* __restrict__ cbnorm)
{
  const int total = 12288 + 65536 + 32768 + 65536 + 32768 + 512;
  for (int i = blockIdx.x*256 + threadIdx.x; i < total; i += gridDim.x*256) {
    int idx = i;
    if (idx < 12288) {
      // encoder conv2 B-frags (bf16 hi/lo), 32x32x16: f=((t*2+nt)*4+kt)
      int j = idx & 7, l6 = (idx >> 3) & 63, f = idx >> 9;
      int kt = f & 3, ntt = (f >> 2) & 1, t = f >> 3;
      int oc = ntt*32 + (l6 & 31);
      int ic = kt*16 + (l6 >> 5)*8 + j;
      float v = w2[(oc*64 + ic)*3 + t];
      ushort_t hi = bf16_rn(v);
      float hf = __uint_as_float(((unsigned)hi) << 16);
      ebhi[idx] = hi; eblo[idx] = bf16_rn(v - hf); continue;
    }
    idx -= 12288;
    if (idx < 65536) {
      // codebook f16 hi/lo frags, scaled x512: ntg16 x kt8
      int j = idx & 7, l6 = (idx >> 3) & 63, f = idx >> 9;
      int kt = f & 7, ntg = f >> 3;
      int k = kt*16 + (l6 >> 5)*8 + j;
      int n = ntg*32 + (l6 & 31);
      float v = cb[n*128 + k] * 512.0f;
      h2u a, b; a.h = (_Float16)v;
      b.h = (_Float16)(v - (float)a.h);
      cbhi[idx] = a.u; cblo[idx] = b.u; continue;
    }
    idx -= 65536;
    if (idx < 32768) {
      int j = idx & 7, l6 = (idx >> 3) & 63, f = idx >> 9;
      int kt = f & 7, ntg = f >> 3;
      int k = kt*16 + (l6 >> 5)*8 + j;
      int n = ntg*32 + (l6 & 31);
      d1f[idx] = bf16_rn(d1w[n*128 + k]); continue;
    }
    idx -= 32768;
    if (idx < 65536) {
      int j = idx & 7, l6 = (idx >> 3) & 63, f = idx >> 9;
      int kt = f & 15, ntg = f >> 4;
      int k = kt*16 + (l6 >> 5)*8 + j;
      int n = ntg*32 + (l6 & 31);
      d2f[idx] = bf16_rn(d2w[n*256 + k]); continue;
    }
    idx -= 65536;
    if (idx < 32768) {
      int j = idx & 7, l6 = (idx >> 3) & 63, f = idx >> 9;
      int kt = f & 15, ntg = f >> 4;
      int k = kt*16 + (l6 >> 5)*8 + j;
      int n = ntg*32 + (l6 & 31);
      d3f[idx] = (n < 100) ? bf16_rn(d3w[n*256 + k]) : (ushort_t)0; continue;
    }
    idx -= 32768;
    { double s = 0.0; const float* c = cb + idx*128;
      for (int e = 0; e < 128; ++e) { double v = (double)c[e]; s += v*v; }
      cbnorm[idx] = (float)s; }
  }
}

// ---------------- encoder: one block per instance, 2 barriers ----------------
// w1,b1,b2,latw,latb NOT __restrict: keep loads in-loop (wave-uniform s_loads / L1).
__global__ __launch_bounds__(256) void encoder_kernel(
    const float* __restrict__ x, const float* __restrict__ tm,
    const float* __restrict__ imask,
    const float* w1, const float* b1,
    const ushort_t* __restrict__ ebhi, const ushort_t* __restrict__ eblo,
    const float* b2, const float* latw, const float* latb,
    ushort_t* zhi, ushort_t* zlo, float* rnp0, float* rnp1)
{
  __shared__ ushort_t s_Hhi[52*72];   // conv1 out bf16-hi: row = pos+1 (rows 0,51 zero)
  __shared__ ushort_t s_Hlo[52*72];
  __shared__ float s_red[2][64];
  const int m = blockIdx.x;
  const int tid = threadIdx.x;
  const int wv   = __builtin_amdgcn_readfirstlane((int)(tid >> 6));
  const int lane = tid & 63;
  const int ln31 = lane & 31, half = lane >> 5;
  const int mt = wv >> 1, nt = wv & 1;
  const int o0 = wv*16;
  const float imv = imask[m];   // uniform -> scalar load

  // B fragments (per-block reloads; L1/L2-hot). Issued early, used after barrier.
  short8 Bh[12], Bl[12];
  {
    const short8* bh8 = (const short8*)ebhi;
    const short8* bl8 = (const short8*)eblo;
    #pragma unroll
    for (int t = 0; t < 3; ++t)
      #pragma unroll
      for (int kt = 0; kt < 4; ++kt) {
        const int f = ((t*2 + nt)*4 + kt);
        Bh[t*4+kt] = bh8[f*64 + lane];
        Bl[t*4+kt] = bl8[f*64 + lane];
      }
  }

  // zero H row 0 (row 51 is written as zeros by lane 50)
  if (tid < 36) { ((unsigned*)s_Hhi)[tid] = 0u; ((unsigned*)s_Hlo)[tid] = 0u; }

  // ---- per-lane x/tm loads (no LDS staging, no barrier) ----
  const long xb = (long)m*100;
  float2 zz; zz.x = 0.f; zz.y = 0.f;
  float2 xL = zz, xC = zz, xR = zz, tL = zz, tC = zz, tR = zz;
  if (lane < 50) {
    xC = *(const float2*)(x  + xb + lane*2);
    tC = *(const float2*)(tm + xb + lane*2);
    if (lane > 0)  { xL = *(const float2*)(x + xb + lane*2 - 2);
                     tL = *(const float2*)(tm + xb + lane*2 - 2); }
    if (lane < 49) { xR = *(const float2*)(x + xb + lane*2 + 2);
                     tR = *(const float2*)(tm + xb + lane*2 + 2); }
  }
  // in[c][pos] = x[2*pos+c]*tm*im ; taps at pos-1, pos, pos+1
  const float inm0 = xL.x*tL.x*imv, inm1 = xL.y*tL.y*imv;
  const float inc0 = xC.x*tC.x*imv, inc1 = xC.y*tC.y*imv;
  const float inp0 = xR.x*tR.x*imv, inp1 = xR.y*tR.y*imv;

  // ---- conv1 (f32) + bf16 hi/lo split, packed b128 LDS writes ----
  {
    ushort_t hi16[16], lo16[16];
    #pragma unroll
    for (int oo = 0; oo < 16; ++oo) {
      const int o = o0 + oo;
      const float* w = w1 + o*6;        // wave-uniform -> s_load
      float h = b1[o];
      h = fmaf(w[0], inm0, h); h = fmaf(w[1], inc0, h); h = fmaf(w[2], inp0, h);
      h = fmaf(w[3], inm1, h); h = fmaf(w[4], inc1, h); h = fmaf(w[5], inp1, h);
      h = fmaxf(h, 0.f);
      if (lane >= 50) h = 0.f;
      const ushort_t hh = bf16_rn(h);
      const float hf = __uint_as_float(((unsigned)hh) << 16);
      hi16[oo] = hh; lo16[oo] = bf16_rn(h - hf);
    }
    if (lane < 51) {
      short8* dh = (short8*)(s_Hhi + (lane+1)*72 + o0);
      short8* dl = (short8*)(s_Hlo + (lane+1)*72 + o0);
      dh[0] = *(short8*)&hi16[0]; dh[1] = *(short8*)&hi16[8];
      dl[0] = *(short8*)&lo16[0]; dl[1] = *(short8*)&lo16[8];
    }
  }
  __syncthreads();   // SYNC 1: H ready

  // ---- conv2 MFMA: 3 taps x 4 k-tiles x 3 passes ----
  f32x16 acc;
  #pragma unroll
  for (int q = 0; q < 16; ++q) acc[q] = 0.f;
  #pragma unroll
  for (int t = 0; t < 3; ++t) {
    int rowA = mt*32 + ln31 + t;
    if (rowA > 51) rowA = 51;
    const int base8 = rowA*9 + half;   // short8 index (72/8 = 9)
    #pragma unroll
    for (int kt = 0; kt < 4; ++kt) {
      const short8 ah = ((const short8*)s_Hhi)[base8 + kt*2];
      const short8 al = ((const short8*)s_Hlo)[base8 + kt*2];
      acc = __builtin_amdgcn_mfma_f32_32x32x16_bf16(ah, Bh[t*4+kt], acc, 0, 0, 0);
      acc = __builtin_amdgcn_mfma_f32_32x32x16_bf16(ah, Bl[t*4+kt], acc, 0, 0, 0);
      acc = __builtin_amdgcn_mfma_f32_32x32x16_bf16(al, Bh[t*4+kt], acc, 0, 0, 0);
    }
  }
  // relu + sum over pos<50
  {
    const float bias2 = b2[nt*32 + ln31];
    float sum = 0.f;
    #pragma unroll
    for (int r = 0; r < 16; ++r) {
      const int mpos = mt*32 + rowfn(r, half);
      const float v = fmaxf(acc[r] + bias2, 0.f);
      if (mpos < 50) sum += v;
    }
    sum += __shfl_xor(sum, 32);
    if (half == 0) s_red[mt][nt*32 + ln31] = sum;
  }
  __syncthreads();   // SYNC 2: s_red ready

  // ---- latent (f32): z[e] = (lat_b + 0.02*sum_ic (red0+red1)[ic]*latw[e][ic]) * imv ----
  if (tid < 128) {
    float a = 0.f;
    const float4* r0 = (const float4*)s_red[0];
    const float4* r1 = (const float4*)s_red[1];
    const float4* wp = (const float4*)(latw + tid*64);
    #pragma unroll
    for (int q = 0; q < 16; ++q) {
      const float4 w4 = wp[q];
      const float4 a4 = r0[q]; const float4 b4 = r1[q];
      a = fmaf(w4.x, a4.x + b4.x, a);
      a = fmaf(w4.y, a4.y + b4.y, a);
      a = fmaf(w4.z, a4.z + b4.z, a);
      a = fmaf(w4.w, a4.w + b4.w, a);
    }
    const float z = fmaf(0.02f, a, latb[tid]) * imv;
    h2u zh; zh.h = (_Float16)z;
    h2u zl; zl.h = (_Float16)(z - (float)zh.h);
    zhi[(long)m*128 + tid] = zh.u;
    zlo[(long)m*128 + tid] = zl.u;
    // rownorm partial per wave (wave0: e=0..63, wave1: e=64..127), no extra barrier
    float v = z*z;
    #pragma unroll
    for (int off = 32; off > 0; off >>= 1) v += __shfl_down(v, off);
    if (lane == 0) { if (wv == 0) rnp0[m] = v; else rnp1[m] = v; }
  }
}

// ---------------- VQ: f16 3-pass MFMA, 32 rows x all 512 codes per block ----------------
__global__ __launch_bounds__(256) void vq_kernel(
    const ushort_t* __restrict__ zhi, const ushort_t* __restrict__ zlo,
    const ushort_t* __restrict__ cbhi, const ushort_t* __restrict__ cblo,
    const float* __restrict__ rnp0, const float* __restrict__ rnp1,
    const float* __restrict__ cbnorm, u64* __restrict__ gbest)
{
  __shared__ ushort_t s_ah[32*136];
  __shared__ ushort_t s_al[32*136];
  __shared__ float s_rn[32];
  __shared__ u64 s_best[32];
  const int tid = threadIdx.x;
  const int m0 = blockIdx.x * 32;
  {
    const short8* gh = (const short8*)(zhi + (long)m0*128);
    const short8* gl = (const short8*)(zlo + (long)m0*128);
    const int row = tid >> 3, c8 = (tid & 7)*2;
    ((short8*)s_ah)[row*17 + c8]     = gh[tid*2];
    ((short8*)s_ah)[row*17 + c8 + 1] = gh[tid*2 + 1];
    ((short8*)s_al)[row*17 + c8]     = gl[tid*2];
    ((short8*)s_al)[row*17 + c8 + 1] = gl[tid*2 + 1];
  }
  if (tid < 32) { s_rn[tid] = rnp0[m0 + tid] + rnp1[m0 + tid]; s_best[tid] = ~0ULL; }
  __syncthreads();

  const int wv = tid >> 6, lane = tid & 63;
  const int ln31 = lane & 31, half = lane >> 5;
  float rnv[16];
  #pragma unroll
  for (int r = 0; r < 16; ++r) rnv[r] = s_rn[rowfn(r, half)];

  u64 best[16];
  #pragma unroll
  for (int r = 0; r < 16; ++r) best[r] = ~0ULL;

  const short8* ch8 = (const short8*)cbhi;
  const short8* cl8 = (const short8*)cblo;
  for (int ct = 0; ct < 4; ++ct) {
    const int ntg = wv*4 + ct;
    half8 Bh[8], Bl[8];
    #pragma unroll
    for (int kt = 0; kt < 8; ++kt) {
      s2h a, b;
      a.s = ch8[(ntg*8 + kt)*64 + lane];
      b.s = cl8[(ntg*8 + kt)*64 + lane];
      Bh[kt] = a.h; Bl[kt] = b.h;
    }
    f32x16 acc;
    #pragma unroll
    for (int q = 0; q < 16; ++q) acc[q] = 0.f;
    const int base8 = ln31*17 + half;
    #pragma unroll
    for (int kt = 0; kt < 8; ++kt) {
      s2h ah, al;
      ah.s = ((const short8*)s_ah)[base8 + kt*2];
      al.s = ((const short8*)s_al)[base8 + kt*2];
      acc = __builtin_amdgcn_mfma_f32_32x32x16_f16(ah.h, Bh[kt], acc, 0, 0, 0);
      acc = __builtin_amdgcn_mfma_f32_32x32x16_f16(ah.h, Bl[kt], acc, 0, 0, 0);
      acc = __builtin_amdgcn_mfma_f32_32x32x16_f16(al.h, Bh[kt], acc, 0, 0, 0);
    }
    const int code = ntg*32 + ln31;
    const float nrm = cbnorm[code];
    #pragma unroll
    for (int r = 0; r < 16; ++r) {
      const float t = fmaf(-0.00390625f, acc[r], rnv[r]);  // A - p/256 (cb scaled x512)
      const float d = t + nrm;
      const u64 pk = ((u64)__float_as_uint(d) << 32) | (u64)(unsigned)code;
      if (pk < best[r]) best[r] = pk;
    }
  }
  #pragma unroll
  for (int r = 0; r < 16; ++r) atomicMin(&s_best[rowfn(r, half)], best[r]);
  __syncthreads();
  if (tid < 32) gbest[m0 + tid] = s_best[tid];
}

// ---------------- decoder GEMM 1 + fused indices/vq-loss/S_im ----------------
__global__ __launch_bounds__(256) void dec1_kernel(
    const float* __restrict__ cb, const u64* __restrict__ gbest,
    const float* __restrict__ imask, const ushort_t* __restrict__ bfrag,
    const float* __restrict__ bias, ushort_t* __restrict__ h1out,
    float* __restrict__ out_idx, float* __restrict__ accums)
{
  __shared__ ushort_t s_a[64*136];
  __shared__ int s_idx[64];
  __shared__ float s_act[64];
  const int tid = threadIdx.x;
  const long m0 = (long)blockIdx.x * 64;
  if (tid < 64) {
    const u64 pk = gbest[m0 + tid];
    const int ii = (int)(unsigned)(pk & 0xffffffffULL);
    const float dd = __uint_as_float((unsigned)(pk >> 32));
    const float imv = imask[m0 + tid];
    s_idx[tid] = ii; s_act[tid] = imv;
    out_idx[m0 + tid] = (imv > 0.f) ? (float)ii : -1.0f;
    float vqp = 1.25f * dd * (1.0f/128.0f) * imv;
    float sim = imv;
    #pragma unroll
    for (int off = 32; off > 0; off >>= 1) {
      vqp += __shfl_down(vqp, off); sim += __shfl_down(sim, off);
    }
    if (tid == 0) { atomicAdd(&accums[1], vqp); atomicAdd(&accums[3], sim); }
  }
  __syncthreads();
  {
    const int row = tid >> 2, seg = tid & 3;
    const float4* src = (const float4*)(cb + (long)s_idx[row]*128 + seg*32);
    const float im = s_act[row];
    ushort_t tmp[32];
    #pragma unroll
    for (int q = 0; q < 8; ++q) {
      const float4 v = src[q];
      tmp[q*4+0] = bf16_rn(v.x*im); tmp[q*4+1] = bf16_rn(v.y*im);
      tmp[q*4+2] = bf16_rn(v.z*im); tmp[q*4+3] = bf16_rn(v.w*im);
    }
    short8* dst = (short8*)(s_a + row*136 + seg*32);
    #pragma unroll
    for (int q = 0; q < 4; ++q) dst[q] = *(short8*)&tmp[q*8];
  }
  __syncthreads();
  const int wv = tid >> 6, lane = tid & 63;
  const int ln31 = lane & 31, half = lane >> 5;
  const short8* bf = (const short8*)bfrag;
  #pragma unroll
  for (int nti = 0; nti < 2; ++nti) {
    const int ntg = wv + nti*4;
    short8 B[8];
    #pragma unroll
    for (int kt = 0; kt < 8; ++kt) B[kt] = bf[(ntg*8 + kt)*64 + lane];
    const float bv = bias[ntg*32 + ln31];
    #pragma unroll
    for (int mtl = 0; mtl < 2; ++mtl) {
      f32x16 acc;
      #pragma unroll
      for (int q = 0; q < 16; ++q) acc[q] = 0.f;
      const int base8 = (mtl*32 + ln31)*17 + half;
      #pragma unroll
      for (int kt = 0; kt < 8; ++kt) {
        const short8 a = ((const short8*)s_a)[base8 + kt*2];
        acc = __builtin_amdgcn_mfma_f32_32x32x16_bf16(a, B[kt], acc, 0, 0, 0);
      }
      const int col = ntg*32 + ln31;
      #pragma unroll
      for (int r = 0; r < 16; ++r) {
        const long row = m0 + mtl*32 + rowfn(r, half);
        h1out[row*256 + col] = bf16_rn(fmaxf(acc[r] + bv, 0.f));
      }
    }
  }
}

// ---------------- decoder GEMM 2: h2 = relu(h1 @ d2^T + b), K=256 ----------------
__global__ __launch_bounds__(256) void dec2_kernel(
    const ushort_t* __restrict__ ain, const ushort_t* __restrict__ bfrag,
    const float* __restrict__ bias, ushort_t* __restrict__ outbuf)
{
  __shared__ ushort_t s_a[64*264];
  const int tid = threadIdx.x;
  const long m0 = (long)blockIdx.x * 64;
  {
    const int row = tid >> 2, seg = tid & 3;
    const short8* src = (const short8*)(ain + (m0 + row)*256 + seg*64);
    short8* dst = (short8*)(s_a + row*264 + seg*64);
    #pragma unroll
    for (int q = 0; q < 8; ++q) dst[q] = src[q];
  }
  __syncthreads();
  const int wv = tid >> 6, lane = tid & 63;
  const int ln31 = lane & 31, half = lane >> 5;
  const short8* bf = (const short8*)bfrag;
  #pragma unroll
  for (int nti = 0; nti < 2; ++nti) {
    const int ntg = wv + nti*4;
    short8 B[16];
    #pragma unroll
    for (int kt = 0; kt < 16; ++kt) B[kt] = bf[(ntg*16 + kt)*64 + lane];
    const float bv = bias[ntg*32 + ln31];
    #pragma unroll
    for (int mtl = 0; mtl < 2; ++mtl) {
      f32x16 acc;
      #pragma unroll
      for (int q = 0; q < 16; ++q) acc[q] = 0.f;
      const int base8 = (mtl*32 + ln31)*33 + half;
      #pragma unroll
      for (int kt = 0; kt < 16; ++kt) {
        const short8 a = ((const short8*)s_a)[base8 + kt*2];
        acc = __builtin_amdgcn_mfma_f32_32x32x16_bf16(a, B[kt], acc, 0, 0, 0);
      }
      const int col = ntg*32 + ln31;
      #pragma unroll
      for (int r = 0; r < 16; ++r) {
        const long row = m0 + mtl*32 + rowfn(r, half);
        outbuf[row*256 + col] = bf16_rn(fmaxf(acc[r] + bv, 0.f));
      }
    }
  }
}

// ---------------- decoder GEMM 3: x_hat + recon loss + S_rw ----------------
__global__ __launch_bounds__(256) void dec3_kernel(
    const ushort_t* __restrict__ ain, const ushort_t* __restrict__ bfrag,
    const float* __restrict__ bias, const float* __restrict__ x,
    const float* __restrict__ tm, const float* __restrict__ imask,
    float* __restrict__ xhat, float* __restrict__ accums)
{
  __shared__ ushort_t s_a[64*264];
  const int tid = threadIdx.x;
  const long m0 = (long)blockIdx.x * 64;
  {
    const int row = tid >> 2, seg = tid & 3;
    const short8* src = (const short8*)(ain + (m0 + row)*256 + seg*64);
    short8* dst = (short8*)(s_a + row*264 + seg*64);
    #pragma unroll
    for (int q = 0; q < 8; ++q) dst[q] = src[q];
  }
  __syncthreads();
  const int wv = tid >> 6, lane = tid & 63;
  const int ln31 = lane & 31, half = lane >> 5;
  const short8* bf = (const short8*)bfrag;
  const int ntg = wv;
  short8 B[16];
  #pragma unroll
  for (int kt = 0; kt < 16; ++kt) B[kt] = bf[(ntg*16 + kt)*64 + lane];
  const int col = ntg*32 + ln31;
  const float bv = (col < 100) ? bias[col] : 0.f;
  float part = 0.f, wsum = 0.f;
  #pragma unroll
  for (int mtl = 0; mtl < 2; ++mtl) {
    f32x16 acc;
    #pragma unroll
    for (int q = 0; q < 16; ++q) acc[q] = 0.f;
    const int base8 = (mtl*32 + ln31)*33 + half;
    #pragma unroll
    for (int kt = 0; kt < 16; ++kt) {
      const short8 a = ((const short8*)s_a)[base8 + kt*2];
      acc = __builtin_amdgcn_mfma_f32_32x32x16_bf16(a, B[kt], acc, 0, 0, 0);
    }
    if (col < 100) {
      #pragma unroll
      for (int r = 0; r < 16; ++r) {
        const long row = m0 + mtl*32 + rowfn(r, half);
        const float xh = acc[r] + bv;
        xhat[row*100 + col] = xh;
        const float wgt = imask[row] * tm[row*100 + col];
        const float df = xh - x[row*100 + col];
        part = fmaf(df*df, wgt, part);
        wsum += wgt;
      }
    }
  }
  #pragma unroll
  for (int off = 32; off > 0; off >>= 1) {
    part += __shfl_down(part, off); wsum += __shfl_down(wsum, off);
  }
  __shared__ float s_p[4], s_w[4];
  if (lane == 0) { s_p[wv] = part; s_w[wv] = wsum; }
  __syncthreads();
  if (tid == 0) {
    atomicAdd(&accums[0], s_p[0]+s_p[1]+s_p[2]+s_p[3]);
    atomicAdd(&accums[2], s_w[0]+s_w[1]+s_w[2]+s_w[3]);
  }
}

// ---------------- finalize scalars ----------------
__global__ void finalize_kernel(const float* __restrict__ accums, float* __restrict__ out) {
  if (threadIdx.x == 0 && blockIdx.x == 0) {
    out[5120000] = accums[0] / fmaxf(accums[2], 1.0f);
    out[5120001] = accums[1] / fmaxf(accums[3], 1.0f);
  }
}

extern "C" void kernel_launch(void* const* d_in, const int* in_sizes, int n_in,
                              void* d_out, int out_size, void* d_ws, size_t ws_size,
                              hipStream_t stream)
{
  (void)in_sizes; (void)n_in; (void)out_size; (void)ws_size;
  const float* x     = (const float*)d_in[0];
  const float* tmsk  = (const float*)d_in[1];
  const float* imask = (const float*)d_in[2];
  const float* w1    = (const float*)d_in[3];
  const float* b1    = (const float*)d_in[4];
  const float* w2    = (const float*)d_in[5];
  const float* b2    = (const float*)d_in[6];
  const float* latw  = (const float*)d_in[7];
  const float* latb  = (const float*)d_in[8];
  const float* cb    = (const float*)d_in[9];
  const float* d1w   = (const float*)d_in[10];
  const float* d1b   = (const float*)d_in[11];
  const float* d2w   = (const float*)d_in[12];
  const float* d2b   = (const float*)d_in[13];
  const float* d3w   = (const float*)d_in[14];
  const float* d3b   = (const float*)d_in[15];
  float* out = (float*)d_out;
  float* ws  = (float*)d_ws;

  float*    rnp0   = ws + WS_RNP0;
  float*    rnp1   = ws + WS_RNP1;
  ushort_t* zhi    = (ushort_t*)(ws + WS_ZHI);
  ushort_t* zlo    = (ushort_t*)(ws + WS_ZLO);
  ushort_t* ebhi   = (ushort_t*)(ws + WS_ENCBHI);
  ushort_t* eblo   = (ushort_t*)(ws + WS_ENCBLO);
  ushort_t* cbhi   = (ushort_t*)(ws + WS_CBHI);
  ushort_t* cblo   = (ushort_t*)(ws + WS_CBLO);
  float*    cbnorm = ws + WS_CBNORM;
  ushort_t* d1f    = (ushort_t*)(ws + WS_D1F);
  ushort_t* d2f    = (ushort_t*)(ws + WS_D2F);
  ushort_t* d3f    = (ushort_t*)(ws + WS_D3F);
  float*    accums = ws + WS_ACCUMS;
  u64*      gbest  = (u64*)(ws + WS_GBEST);
  ushort_t* h1     = (ushort_t*)(ws + WS_H1);
  ushort_t* h2     = (ushort_t*)(ws + WS_H2);
  float* xhat    = out;
  float* out_idx = out + 5120002;

  hipMemsetAsync(accums, 0, 8*sizeof(float), stream);

  prep_kernel<<<512, 256, 0, stream>>>(w2, cb, d1w, d2w, d3w,
                                       ebhi, eblo, cbhi, cblo, d1f, d2f, d3f, cbnorm);
  encoder_kernel<<<51200, 256, 0, stream>>>(x, tmsk, imask, w1, b1, ebhi, eblo, b2,
                                            latw, latb, zhi, zlo, rnp0, rnp1);
  vq_kernel<<<1600, 256, 0, stream>>>(zhi, zlo, cbhi, cblo, rnp0, rnp1, cbnorm, gbest);
  dec1_kernel<<<800, 256, 0, stream>>>(cb, gbest, imask, d1f, d1b, h1, out_idx, accums);
  dec2_kernel<<<800, 256, 0, stream>>>(h1, d2f, d2b, h2);
  dec3_kernel<<<800, 256, 0, stream>>>(h2, d3f, d3b, x, tmsk, imask, xhat, accums);
  finalize_kernel<<<1, 64, 0, stream>>>(accums, out);
}

// Round 6
// 621.499 us; speedup vs baseline: 3.0568x; 1.1822x over previous
//
#include <hip/hip_runtime.h>
#include <stdint.h>

typedef unsigned long long u64;
typedef unsigned short ushort_t;
typedef __attribute__((ext_vector_type(8))) short short8;
typedef __attribute__((ext_vector_type(8))) _Float16 half8;
typedef __attribute__((ext_vector_type(16))) float f32x16;

// Dims: B=512,N=100 -> M=51200; T=100, L=50 conv pos, HE=64, E=128, NE=512, HD=256.

// ---------------- workspace layout (float offsets) ----------------
#define WS_RNP0     0ll          // 51200 f32 (rownorm partial wave0)  -> end    51,200
#define WS_RNP1     51200ll      // 51200 f32 (partial wave1)          -> end   102,400
#define WS_ZHI      102400ll     // 51200*128 ushort = 3,276,800 f     -> end 3,379,200
#define WS_ZLO      3379200ll    // 3,276,800 f                        -> end 6,656,000
#define WS_ENCBHI   6656000ll    // 12288 ushort = 6144 f              -> end 6,662,144
#define WS_ENCBLO   6662144ll    // 6144 f                             -> end 6,668,288
#define WS_CBHI     6668288ll    // 65536 ushort = 32768 f             -> end 6,701,056
#define WS_CBLO     6701056ll    // 32768 f                            -> end 6,733,824
#define WS_CBNORM   6733824ll    // 512 f                              -> end 6,734,336
#define WS_D1F      6734336ll    // 32768 ushort = 16384 f             -> end 6,750,720
#define WS_D2F      6750720ll    // 65536 ushort = 32768 f             -> end 6,783,488
#define WS_D3F      6783488ll    // 32768 ushort = 16384 f             -> end 6,799,872
#define WS_ACCUMS   6799872ll    // 8 f32                              -> end 6,799,880
#define WS_GBEST    6799880ll    // 51200 u64 = 102,400 f (byte%8==0)  -> end 6,902,280
#define WS_H1       6902280ll    // 51200*256 ushort = 6,553,600 f     -> end 13,455,880
#define WS_H2       13455880ll   // 6,553,600 f                        -> end 20,009,480 (~80 MB)

__device__ __host__ inline ushort_t bf16_rn(float v) {
  unsigned u = __float_as_uint(v);
  unsigned r = (u + 0x7fffu + ((u >> 16) & 1u)) >> 16;
  return (ushort_t)r;
}
union h2u { _Float16 h; unsigned short u; };
union s2h { short8 s; half8 h; };

__device__ inline int rowfn(int r, int half) { return (r & 3) + 8*(r >> 2) + 4*half; }

// ---------------- prep: frag-pack all weights + codebook norms ----------------
__global__ __launch_bounds__(256) void prep_kernel(
    const float* __restrict__ w2, const float* __restrict__ cb,
    const float* __restrict__ d1w, const float* __restrict__ d2w,
    const float* __restrict__ d3w,
    ushort_t* __restrict__ ebhi, ushort_t* __restrict__ eblo,
    ushort_t* __restrict__ cbhi, ushort_t* __restrict__ cblo,
    ushort_t* __restrict__ d1f, ushort_t* __restrict__ d2f,
    ushort_t* __restrict__ d3f, float* __restrict__ cbnorm)
{
  const int total = 12288 + 65536 + 32768 + 65536 + 32768 + 512;
  for (int i = blockIdx.x*256 + threadIdx.x; i < total; i += gridDim.x*256) {
    int idx = i;
    if (idx < 12288) {
      // encoder conv2 B-frags (bf16 hi/lo), 32x32x16: f=((t*2+nt)*4+kt)
      int j = idx & 7, l6 = (idx >> 3) & 63, f = idx >> 9;
      int kt = f & 3, ntt = (f >> 2) & 1, t = f >> 3;
      int oc = ntt*32 + (l6 & 31);
      int ic = kt*16 + (l6 >> 5)*8 + j;
      float v = w2[(oc*64 + ic)*3 + t];
      ushort_t hi = bf16_rn(v);
      float hf = __uint_as_float(((unsigned)hi) << 16);
      ebhi[idx] = hi; eblo[idx] = bf16_rn(v - hf); continue;
    }
    idx -= 12288;
    if (idx < 65536) {
      // codebook f16 hi/lo frags, scaled x512: ntg16 x kt8
      int j = idx & 7, l6 = (idx >> 3) & 63, f = idx >> 9;
      int kt = f & 7, ntg = f >> 3;
      int k = kt*16 + (l6 >> 5)*8 + j;
      int n = ntg*32 + (l6 & 31);
      float v = cb[n*128 + k] * 512.0f;
      h2u a, b; a.h = (_Float16)v;
      b.h = (_Float16)(v - (float)a.h);
      cbhi[idx] = a.u; cblo[idx] = b.u; continue;
    }
    idx -= 65536;
    if (idx < 32768) {
      int j = idx & 7, l6 = (idx >> 3) & 63, f = idx >> 9;
      int kt = f & 7, ntg = f >> 3;
      int k = kt*16 + (l6 >> 5)*8 + j;
      int n = ntg*32 + (l6 & 31);
      d1f[idx] = bf16_rn(d1w[n*128 + k]); continue;
    }
    idx -= 32768;
    if (idx < 65536) {
      int j = idx & 7, l6 = (idx >> 3) & 63, f = idx >> 9;
      int kt = f & 15, ntg = f >> 4;
      int k = kt*16 + (l6 >> 5)*8 + j;
      int n = ntg*32 + (l6 & 31);
      d2f[idx] = bf16_rn(d2w[n*256 + k]); continue;
    }
    idx -= 65536;
    if (idx < 32768) {
      int j = idx & 7, l6 = (idx >> 3) & 63, f = idx >> 9;
      int kt = f & 15, ntg = f >> 4;
      int k = kt*16 + (l6 >> 5)*8 + j;
      int n = ntg*32 + (l6 & 31);
      d3f[idx] = (n < 100) ? bf16_rn(d3w[n*256 + k]) : (ushort_t)0; continue;
    }
    idx -= 32768;
    { double s = 0.0; const float* c = cb + idx*128;
      for (int e = 0; e < 128; ++e) { double v = (double)c[e]; s += v*v; }
      cbnorm[idx] = (float)s; }
  }
}

// ---------------- encoder: R2 skeleton (LDS x-staging, low VGPR), 3 barriers ----------------
// w1,b1,b2,latw,latb NOT __restrict: keep loads in-loop (wave-uniform s_loads / L1).
__global__ __launch_bounds__(256) void encoder_kernel(
    const float* __restrict__ x, const float* __restrict__ tm,
    const float* __restrict__ imask,
    const float* w1, const float* b1,
    const ushort_t* __restrict__ ebhi, const ushort_t* __restrict__ eblo,
    const float* b2, const float* latw, const float* latb,
    ushort_t* zhi, ushort_t* zlo, float* rnp0, float* rnp1)
{
  __shared__ float s_h0[104];         // 2 channels, halo'd length 52
  __shared__ ushort_t s_Hhi[52*72];   // conv1 out bf16-hi: row = pos+1 (rows 0,51 zero)
  __shared__ ushort_t s_Hlo[52*72];
  __shared__ float s_red[2][64];
  const int m = blockIdx.x;
  const int tid = threadIdx.x;
  const int wv   = __builtin_amdgcn_readfirstlane((int)(tid >> 6));
  const int lane = tid & 63;
  const int ln31 = lane & 31, half = lane >> 5;
  const int mt = wv >> 1, nt = wv & 1;
  const int o0 = wv*16;
  const float imv = imask[m];   // uniform -> scalar load

  // one-time LDS zero init (visible after SYNC_B / SYNC_C)
  if (tid < 2)  { s_h0[tid*52] = 0.f; s_h0[tid*52 + 51] = 0.f; }
  if (tid < 36) { ((unsigned*)s_Hhi)[tid] = 0u; ((unsigned*)s_Hlo)[tid] = 0u; }  // H row 0

  // ---- x/tm staged via LDS (keeps VGPR low; 100 threads, 1 float2 each) ----
  if (tid < 100) {
    // channel c = tid&1, pos l = tid>>1
    s_h0[(tid & 1)*52 + 1 + (tid >> 1)] =
        x[(long)m*100 + tid] * tm[(long)m*100 + tid] * imv;
  }
  __syncthreads();   // SYNC_B: s_h0 ready

  // ---- conv1 (f32) + bf16 hi/lo split, packed b128 LDS writes ----
  {
    const int ll = (lane < 50) ? lane : 0;
    const float a0 = s_h0[ll],    a1 = s_h0[ll+1],    a2 = s_h0[ll+2];
    const float c0 = s_h0[52+ll], c1 = s_h0[52+ll+1], c2 = s_h0[52+ll+2];
    ushort_t hi16[16], lo16[16];
    #pragma unroll
    for (int oo = 0; oo < 16; ++oo) {
      const int o = o0 + oo;
      const float* w = w1 + o*6;        // wave-uniform -> s_load
      float h = b1[o];
      h = fmaf(w[0], a0, h); h = fmaf(w[1], a1, h); h = fmaf(w[2], a2, h);
      h = fmaf(w[3], c0, h); h = fmaf(w[4], c1, h); h = fmaf(w[5], c2, h);
      h = fmaxf(h, 0.f);
      if (lane >= 50) h = 0.f;
      const ushort_t hh = bf16_rn(h);
      const float hf = __uint_as_float(((unsigned)hh) << 16);
      hi16[oo] = hh; lo16[oo] = bf16_rn(h - hf);
    }
    if (lane < 51) {
      short8* dh = (short8*)(s_Hhi + (lane+1)*72 + o0);
      short8* dl = (short8*)(s_Hlo + (lane+1)*72 + o0);
      dh[0] = *(short8*)&hi16[0]; dh[1] = *(short8*)&hi16[8];
      dl[0] = *(short8*)&lo16[0]; dl[1] = *(short8*)&lo16[8];
    }
  }
  __syncthreads();   // SYNC_C: H ready

  // ---- conv2 MFMA: 3 taps x 4 k-tiles x 3 passes (B-frags loaded just-in-time) ----
  f32x16 acc;
  #pragma unroll
  for (int q = 0; q < 16; ++q) acc[q] = 0.f;
  {
    const short8* bh8 = (const short8*)ebhi;
    const short8* bl8 = (const short8*)eblo;
    #pragma unroll
    for (int t = 0; t < 3; ++t) {
      int rowA = mt*32 + ln31 + t;
      if (rowA > 51) rowA = 51;
      const int base8 = rowA*9 + half;   // short8 index (72/8 = 9)
      #pragma unroll
      for (int kt = 0; kt < 4; ++kt) {
        const int f = ((t*2 + nt)*4 + kt);
        const short8 Bh = bh8[f*64 + lane];
        const short8 Bl = bl8[f*64 + lane];
        const short8 ah = ((const short8*)s_Hhi)[base8 + kt*2];
        const short8 al = ((const short8*)s_Hlo)[base8 + kt*2];
        acc = __builtin_amdgcn_mfma_f32_32x32x16_bf16(ah, Bh, acc, 0, 0, 0);
        acc = __builtin_amdgcn_mfma_f32_32x32x16_bf16(ah, Bl, acc, 0, 0, 0);
        acc = __builtin_amdgcn_mfma_f32_32x32x16_bf16(al, Bh, acc, 0, 0, 0);
      }
    }
  }
  // relu + sum over pos<50
  {
    const float bias2 = b2[nt*32 + ln31];
    float sum = 0.f;
    #pragma unroll
    for (int r = 0; r < 16; ++r) {
      const int mpos = mt*32 + rowfn(r, half);
      const float v = fmaxf(acc[r] + bias2, 0.f);
      if (mpos < 50) sum += v;
    }
    sum += __shfl_xor(sum, 32);
    if (half == 0) s_red[mt][nt*32 + ln31] = sum;
  }
  __syncthreads();   // SYNC_D: s_red ready

  // ---- latent (f32): z[e] = (lat_b + 0.02*sum_ic (red0+red1)[ic]*latw[e][ic]) * imv ----
  if (tid < 128) {
    float a = 0.f;
    const float4* r0 = (const float4*)s_red[0];
    const float4* r1 = (const float4*)s_red[1];
    const float4* wp = (const float4*)(latw + tid*64);
    #pragma unroll
    for (int q = 0; q < 16; ++q) {
      const float4 w4 = wp[q];
      const float4 a4 = r0[q]; const float4 b4 = r1[q];
      a = fmaf(w4.x, a4.x + b4.x, a);
      a = fmaf(w4.y, a4.y + b4.y, a);
      a = fmaf(w4.z, a4.z + b4.z, a);
      a = fmaf(w4.w, a4.w + b4.w, a);
    }
    const float z = fmaf(0.02f, a, latb[tid]) * imv;
    h2u zh; zh.h = (_Float16)z;
    h2u zl; zl.h = (_Float16)(z - (float)zh.h);
    zhi[(long)m*128 + tid] = zh.u;
    zlo[(long)m*128 + tid] = zl.u;
    // rownorm partial per wave (wave0: e=0..63, wave1: e=64..127), no extra barrier
    float v = z*z;
    #pragma unroll
    for (int off = 32; off > 0; off >>= 1) v += __shfl_down(v, off);
    if (lane == 0) { if (wv == 0) rnp0[m] = v; else rnp1[m] = v; }
  }
}

// ---------------- VQ: f16 3-pass MFMA, 32 rows x all 512 codes per block ----------------
__global__ __launch_bounds__(256) void vq_kernel(
    const ushort_t* __restrict__ zhi, const ushort_t* __restrict__ zlo,
    const ushort_t* __restrict__ cbhi, const ushort_t* __restrict__ cblo,
    const float* __restrict__ rnp0, const float* __restrict__ rnp1,
    const float* __restrict__ cbnorm, u64* __restrict__ gbest)
{
  __shared__ ushort_t s_ah[32*136];
  __shared__ ushort_t s_al[32*136];
  __shared__ float s_rn[32];
  __shared__ u64 s_best[32];
  const int tid = threadIdx.x;
  const int m0 = blockIdx.x * 32;
  {
    const short8* gh = (const short8*)(zhi + (long)m0*128);
    const short8* gl = (const short8*)(zlo + (long)m0*128);
    const int row = tid >> 3, c8 = (tid & 7)*2;
    ((short8*)s_ah)[row*17 + c8]     = gh[tid*2];
    ((short8*)s_ah)[row*17 + c8 + 1] = gh[tid*2 + 1];
    ((short8*)s_al)[row*17 + c8]     = gl[tid*2];
    ((short8*)s_al)[row*17 + c8 + 1] = gl[tid*2 + 1];
  }
  if (tid < 32) { s_rn[tid] = rnp0[m0 + tid] + rnp1[m0 + tid]; s_best[tid] = ~0ULL; }
  __syncthreads();

  const int wv = tid >> 6, lane = tid & 63;
  const int ln31 = lane & 31, half = lane >> 5;
  float rnv[16];
  #pragma unroll
  for (int r = 0; r < 16; ++r) rnv[r] = s_rn[rowfn(r, half)];

  u64 best[16];
  #pragma unroll
  for (int r = 0; r < 16; ++r) best[r] = ~0ULL;

  const short8* ch8 = (const short8*)cbhi;
  const short8* cl8 = (const short8*)cblo;
  for (int ct = 0; ct < 4; ++ct) {
    const int ntg = wv*4 + ct;
    half8 Bh[8], Bl[8];
    #pragma unroll
    for (int kt = 0; kt < 8; ++kt) {
      s2h a, b;
      a.s = ch8[(ntg*8 + kt)*64 + lane];
      b.s = cl8[(ntg*8 + kt)*64 + lane];
      Bh[kt] = a.h; Bl[kt] = b.h;
    }
    f32x16 acc;
    #pragma unroll
    for (int q = 0; q < 16; ++q) acc[q] = 0.f;
    const int base8 = ln31*17 + half;
    #pragma unroll
    for (int kt = 0; kt < 8; ++kt) {
      s2h ah, al;
      ah.s = ((const short8*)s_ah)[base8 + kt*2];
      al.s = ((const short8*)s_al)[base8 + kt*2];
      acc = __builtin_amdgcn_mfma_f32_32x32x16_f16(ah.h, Bh[kt], acc, 0, 0, 0);
      acc = __builtin_amdgcn_mfma_f32_32x32x16_f16(ah.h, Bl[kt], acc, 0, 0, 0);
      acc = __builtin_amdgcn_mfma_f32_32x32x16_f16(al.h, Bh[kt], acc, 0, 0, 0);
    }
    const int code = ntg*32 + ln31;
    const float nrm = cbnorm[code];
    #pragma unroll
    for (int r = 0; r < 16; ++r) {
      const float t = fmaf(-0.00390625f, acc[r], rnv[r]);  // A - p/256 (cb scaled x512)
      const float d = t + nrm;
      const u64 pk = ((u64)__float_as_uint(d) << 32) | (u64)(unsigned)code;
      if (pk < best[r]) best[r] = pk;
    }
  }
  #pragma unroll
  for (int r = 0; r < 16; ++r) atomicMin(&s_best[rowfn(r, half)], best[r]);
  __syncthreads();
  if (tid < 32) gbest[m0 + tid] = s_best[tid];
}

// ---------------- decoder GEMM 1 + fused indices/vq-loss/S_im ----------------
__global__ __launch_bounds__(256) void dec1_kernel(
    const float* __restrict__ cb, const u64* __restrict__ gbest,
    const float* __restrict__ imask, const ushort_t* __restrict__ bfrag,
    const float* __restrict__ bias, ushort_t* __restrict__ h1out,
    float* __restrict__ out_idx, float* __restrict__ accums)
{
  __shared__ ushort_t s_a[64*136];
  __shared__ int s_idx[64];
  __shared__ float s_act[64];
  const int tid = threadIdx.x;
  const long m0 = (long)blockIdx.x * 64;
  if (tid < 64) {
    const u64 pk = gbest[m0 + tid];
    const int ii = (int)(unsigned)(pk & 0xffffffffULL);
    const float dd = __uint_as_float((unsigned)(pk >> 32));
    const float imv = imask[m0 + tid];
    s_idx[tid] = ii; s_act[tid] = imv;
    out_idx[m0 + tid] = (imv > 0.f) ? (float)ii : -1.0f;
    float vqp = 1.25f * dd * (1.0f/128.0f) * imv;
    float sim = imv;
    #pragma unroll
    for (int off = 32; off > 0; off >>= 1) {
      vqp += __shfl_down(vqp, off); sim += __shfl_down(sim, off);
    }
    if (tid == 0) { atomicAdd(&accums[1], vqp); atomicAdd(&accums[3], sim); }
  }
  __syncthreads();
  {
    const int row = tid >> 2, seg = tid & 3;
    const float4* src = (const float4*)(cb + (long)s_idx[row]*128 + seg*32);
    const float im = s_act[row];
    ushort_t tmp[32];
    #pragma unroll
    for (int q = 0; q < 8; ++q) {
      const float4 v = src[q];
      tmp[q*4+0] = bf16_rn(v.x*im); tmp[q*4+1] = bf16_rn(v.y*im);
      tmp[q*4+2] = bf16_rn(v.z*im); tmp[q*4+3] = bf16_rn(v.w*im);
    }
    short8* dst = (short8*)(s_a + row*136 + seg*32);
    #pragma unroll
    for (int q = 0; q < 4; ++q) dst[q] = *(short8*)&tmp[q*8];
  }
  __syncthreads();
  const int wv = tid >> 6, lane = tid & 63;
  const int ln31 = lane & 31, half = lane >> 5;
  const short8* bf = (const short8*)bfrag;
  #pragma unroll
  for (int nti = 0; nti < 2; ++nti) {
    const int ntg = wv + nti*4;
    short8 B[8];
    #pragma unroll
    for (int kt = 0; kt < 8; ++kt) B[kt] = bf[(ntg*8 + kt)*64 + lane];
    const float bv = bias[ntg*32 + ln31];
    #pragma unroll
    for (int mtl = 0; mtl < 2; ++mtl) {
      f32x16 acc;
      #pragma unroll
      for (int q = 0; q < 16; ++q) acc[q] = 0.f;
      const int base8 = (mtl*32 + ln31)*17 + half;
      #pragma unroll
      for (int kt = 0; kt < 8; ++kt) {
        const short8 a = ((const short8*)s_a)[base8 + kt*2];
        acc = __builtin_amdgcn_mfma_f32_32x32x16_bf16(a, B[kt], acc, 0, 0, 0);
      }
      const int col = ntg*32 + ln31;
      #pragma unroll
      for (int r = 0; r < 16; ++r) {
        const long row = m0 + mtl*32 + rowfn(r, half);
        h1out[row*256 + col] = bf16_rn(fmaxf(acc[r] + bv, 0.f));
      }
    }
  }
}

// ---------------- decoder GEMM 2: h2 = relu(h1 @ d2^T + b), K=256 ----------------
__global__ __launch_bounds__(256) void dec2_kernel(
    const ushort_t* __restrict__ ain, const ushort_t* __restrict__ bfrag,
    const float* __restrict__ bias, ushort_t* __restrict__ outbuf)
{
  __shared__ ushort_t s_a[64*264];
  const int tid = threadIdx.x;
  const long m0 = (long)blockIdx.x * 64;
  {
    const int row = tid >> 2, seg = tid & 3;
    const short8* src = (const short8*)(ain + (m0 + row)*256 + seg*64);
    short8* dst = (short8*)(s_a + row*264 + seg*64);
    #pragma unroll
    for (int q = 0; q < 8; ++q) dst[q] = src[q];
  }
  __syncthreads();
  const int wv = tid >> 6, lane = tid & 63;
  const int ln31 = lane & 31, half = lane >> 5;
  const short8* bf = (const short8*)bfrag;
  #pragma unroll
  for (int nti = 0; nti < 2; ++nti) {
    const int ntg = wv + nti*4;
    short8 B[16];
    #pragma unroll
    for (int kt = 0; kt < 16; ++kt) B[kt] = bf[(ntg*16 + kt)*64 + lane];
    const float bv = bias[ntg*32 + ln31];
    #pragma unroll
    for (int mtl = 0; mtl < 2; ++mtl) {
      f32x16 acc;
      #pragma unroll
      for (int q = 0; q < 16; ++q) acc[q] = 0.f;
      const int base8 = (mtl*32 + ln31)*33 + half;
      #pragma unroll
      for (int kt = 0; kt < 16; ++kt) {
        const short8 a = ((const short8*)s_a)[base8 + kt*2];
        acc = __builtin_amdgcn_mfma_f32_32x32x16_bf16(a, B[kt], acc, 0, 0, 0);
      }
      const int col = ntg*32 + ln31;
      #pragma unroll
      for (int r = 0; r < 16; ++r) {
        const long row = m0 + mtl*32 + rowfn(r, half);
        outbuf[row*256 + col] = bf16_rn(fmaxf(acc[r] + bv, 0.f));
      }
    }
  }
}

// ---------------- decoder GEMM 3: x_hat + recon loss + S_rw ----------------
__global__ __launch_bounds__(256) void dec3_kernel(
    const ushort_t* __restrict__ ain, const ushort_t* __restrict__ bfrag,
    const float* __restrict__ bias, const float* __restrict__ x,
    const float* __restrict__ tm, const float* __restrict__ imask,
    float* __restrict__ xhat, float* __restrict__ accums)
{
  __shared__ ushort_t s_a[64*264];
  const int tid = threadIdx.x;
  const long m0 = (long)blockIdx.x * 64;
  {
    const int row = tid >> 2, seg = tid & 3;
    const short8* src = (const short8*)(ain + (m0 + row)*256 + seg*64);
    short8* dst = (short8*)(s_a + row*264 + seg*64);
    #pragma unroll
    for (int q = 0; q < 8; ++q) dst[q] = src[q];
  }
  __syncthreads();
  const int wv = tid >> 6, lane = tid & 63;
  const int ln31 = lane & 31, half = lane >> 5;
  const short8* bf = (const short8*)bfrag;
  const int ntg = wv;
  short8 B[16];
  #pragma unroll
  for (int kt = 0; kt < 16; ++kt) B[kt] = bf[(ntg*16 + kt)*64 + lane];
  const int col = ntg*32 + ln31;
  const float bv = (col < 100) ? bias[col] : 0.f;
  float part = 0.f, wsum = 0.f;
  #pragma unroll
  for (int mtl = 0; mtl < 2; ++mtl) {
    f32x16 acc;
    #pragma unroll
    for (int q = 0; q < 16; ++q) acc[q] = 0.f;
    const int base8 = (mtl*32 + ln31)*33 + half;
    #pragma unroll
    for (int kt = 0; kt < 16; ++kt) {
      const short8 a = ((const short8*)s_a)[base8 + kt*2];
      acc = __builtin_amdgcn_mfma_f32_32x32x16_bf16(a, B[kt], acc, 0, 0, 0);
    }
    if (col < 100) {
      #pragma unroll
      for (int r = 0; r < 16; ++r) {
        const long row = m0 + mtl*32 + rowfn(r, half);
        const float xh = acc[r] + bv;
        xhat[row*100 + col] = xh;
        const float wgt = imask[row] * tm[row*100 + col];
        const float df = xh - x[row*100 + col];
        part = fmaf(df*df, wgt, part);
        wsum += wgt;
      }
    }
  }
  #pragma unroll
  for (int off = 32; off > 0; off >>= 1) {
    part += __shfl_down(part, off); wsum += __shfl_down(wsum, off);
  }
  __shared__ float s_p[4], s_w[4];
  if (lane == 0) { s_p[wv] = part; s_w[wv] = wsum; }
  __syncthreads();
  if (tid == 0) {
    atomicAdd(&accums[0], s_p[0]+s_p[1]+s_p[2]+s_p[3]);
    atomicAdd(&accums[2], s_w[0]+s_w[1]+s_w[2]+s_w[3]);
  }
}

// ---------------- finalize scalars ----------------
__global__ void finalize_kernel(const float* __restrict__ accums, float* __restrict__ out) {
  if (threadIdx.x == 0 && blockIdx.x == 0) {
    out[5120000] = accums[0] / fmaxf(accums[2], 1.0f);
    out[5120001] = accums[1] / fmaxf(accums[3], 1.0f);
  }
}

extern "C" void kernel_launch(void* const* d_in, const int* in_sizes, int n_in,
                              void* d_out, int out_size, void* d_ws, size_t ws_size,
                              hipStream_t stream)
{
  (void)in_sizes; (void)n_in; (void)out_size; (void)ws_size;
  const float* x     = (const float*)d_in[0];
  const float* tmsk  = (const float*)d_in[1];
  const float* imask = (const float*)d_in[2];
  const float* w1    = (const float*)d_in[3];
  const float* b1    = (const float*)d_in[4];
  const float* w2    = (const float*)d_in[5];
  const float* b2    = (const float*)d_in[6];
  const float* latw  = (const float*)d_in[7];
  const float* latb  = (const float*)d_in[8];
  const float* cb    = (const float*)d_in[9];
  const float* d1w   = (const float*)d_in[10];
  const float* d1b   = (const float*)d_in[11];
  const float* d2w   = (const float*)d_in[12];
  const float* d2b   = (const float*)d_in[13];
  const float* d3w   = (const float*)d_in[14];
  const float* d3b   = (const float*)d_in[15];
  float* out = (float*)d_out;
  float* ws  = (float*)d_ws;

  float*    rnp0   = ws + WS_RNP0;
  float*    rnp1   = ws + WS_RNP1;
  ushort_t* zhi    = (ushort_t*)(ws + WS_ZHI);
  ushort_t* zlo    = (ushort_t*)(ws + WS_ZLO);
  ushort_t* ebhi   = (ushort_t*)(ws + WS_ENCBHI);
  ushort_t* eblo   = (ushort_t*)(ws + WS_ENCBLO);
  ushort_t* cbhi   = (ushort_t*)(ws + WS_CBHI);
  ushort_t* cblo   = (ushort_t*)(ws + WS_CBLO);
  float*    cbnorm = ws + WS_CBNORM;
  ushort_t* d1f    = (ushort_t*)(ws + WS_D1F);
  ushort_t* d2f    = (ushort_t*)(ws + WS_D2F);
  ushort_t* d3f    = (ushort_t*)(ws + WS_D3F);
  float*    accums = ws + WS_ACCUMS;
  u64*      gbest  = (u64*)(ws + WS_GBEST);
  ushort_t* h1     = (ushort_t*)(ws + WS_H1);
  ushort_t* h2     = (ushort_t*)(ws + WS_H2);
  float* xhat    = out;
  float* out_idx = out + 5120002;

  hipMemsetAsync(accums, 0, 8*sizeof(float), stream);

  prep_kernel<<<512, 256, 0, stream>>>(w2, cb, d1w, d2w, d3w,
                                       ebhi, eblo, cbhi, cblo, d1f, d2f, d3f, cbnorm);
  encoder_kernel<<<51200, 256, 0, stream>>>(x, tmsk, imask, w1, b1, ebhi, eblo, b2,
                                            latw, latb, zhi, zlo, rnp0, rnp1);
  vq_kernel<<<1600, 256, 0, stream>>>(zhi, zlo, cbhi, cblo, rnp0, rnp1, cbnorm, gbest);
  dec1_kernel<<<800, 256, 0, stream>>>(cb, gbest, imask, d1f, d1b, h1, out_idx, accums);
  dec2_kernel<<<800, 256, 0, stream>>>(h1, d2f, d2b, h2);
  dec3_kernel<<<800, 256, 0, stream>>>(h2, d3f, d3b, x, tmsk, imask, xhat, accums);
  finalize_kernel<<<1, 64, 0, stream>>>(accums, out);
}